// Round 13
// baseline (4434.063 us; speedup 1.0000x reference)
//
#include <hip/hip_runtime.h>

#define DEV __device__ __forceinline__

typedef __attribute__((ext_vector_type(4))) float f32x4;
typedef __attribute__((ext_vector_type(8))) short s16x8;
typedef __attribute__((ext_vector_type(8))) unsigned short u16x8;

static const int NTOK = 8192;      // B*S
static const int DD   = 1024;      // D
static const int NNEU = 32768;     // N
static const int NC   = 8192;      // chunk width (4 chunks)
static const int NREP = 8;         // stat replication (contention fix)

// output layout (floats)
static const int OUT_ACT    = 8388608;
static const int OUT_GMAX   = 8396800;
static const int OUT_SLB    = 8404992;
static const int OUT_SSTD   = 8404993;
static const int OUT_ES     = 8404994;
static const int OUT_ANM    = 8404995;
static const int OUT_STRONG = 8404996;
static const int OUT_PHIB   = 8413188;
static const int OUT_ZMEAN  = 8421380;
static const int OUT_TAUM   = 8429572;
static const int OUT_Z75    = 8429573;
static const int OUT_Z30    = 8429574;
static const int OUT_SKEW   = 8429575;
static const int OUT_ASTD   = 8429576;
static const int OUT_ENT    = 8429577;

DEV unsigned short f2bf(float f){
  unsigned u = __float_as_uint(f);
  u += 0x7fffu + ((u >> 16) & 1u);
  return (unsigned short)(u >> 16);
}
DEV float bf2f(unsigned short h){ return __uint_as_float(((unsigned)h) << 16); }
DEV float rnd_bf(float f){ return bf2f(f2bf(f)); }

template<int AUX>
DEV void gl_lds16(const void* g, void* l){
  __builtin_amdgcn_global_load_lds(
      (const __attribute__((address_space(1))) unsigned int*)g,
      (__attribute__((address_space(3))) unsigned int*)l, 16, 0, AUX);
}

DEV f32x4 mfma16(s16x8 a, s16x8 b, f32x4 c){
  return __builtin_amdgcn_mfma_f32_16x16x32_bf16(a, b, c, 0, 0, 0);
}

// stage one 128x64 bf16 tile (16KB): XOR-swizzled source, linear LDS dest.
template<int AUX>
DEV void stage4(const unsigned short* __restrict__ G, size_t ld, int k0,
                unsigned short* L, int t){
  #pragma unroll
  for (int i = 0; i < 4; i++){
    int ch = i*256 + t;
    int row = ch >> 3, c = ch & 7;
    int cs = c ^ (row & 7);
    int wb = (i*256 + (t & 192)) * 16;
    gl_lds16<AUX>(G + (size_t)row * ld + k0 + cs*8, (char*)L + wb);
  }
}

// stage one 128x128 bf16 tile (32KB) of S: chunk-XOR swizzle c^(row&15)
template<int AUX>
DEV void stageS(const unsigned short* __restrict__ S0, size_t ldS,
                unsigned short* L, int t){
  #pragma unroll
  for (int i = 0; i < 8; i++){
    int ch = i*256 + t;
    int row = ch >> 4, c = ch & 15;
    int cs = c ^ (row & 15);
    int wb = (i*256 + (t & 192)) * 16;
    gl_lds16<AUX>(S0 + (size_t)row * ldS + cs*8, (char*)L + wb);
  }
}

// swizzled fragment read: logical (row R, k = kk + lq*8)
DEV s16x8 frg(const unsigned short* L, int R, int kk, int lq){
  int cc = ((kk >> 3) + lq) ^ (R & 7);
  return *(const s16x8*)((const char*)L + R*128 + cc*16);
}

DEV void waitv_bar(){
  asm volatile("s_waitcnt vmcnt(0)" ::: "memory");
  __builtin_amdgcn_s_barrier();
  __builtin_amdgcn_sched_barrier(0);
}

// 8x8-square XCD-banded remap for (64,64) grids.
DEV int2 xcd64(){
  int orig = blockIdx.y * 64 + blockIdx.x;
  int xcd = orig & 7, p = orig >> 3;
  int sqy = p >> 6, off = p & 63;
  int2 r;
  r.x = xcd*8 + (off & 7);
  r.y = sqy*8 + (off >> 3);
  return r;
}

// ---------------- preprocessing ----------------

template<int RND, int PNS>
__global__ __launch_bounds__(256) void k_rncast(const float* __restrict__ in,
    unsigned short* __restrict__ o, const float* __restrict__ hs,
    float* __restrict__ ns){
  __shared__ float hsh[1024];
  __shared__ float pr[8];
  int t = threadIdx.x, l = t & 63, wv = t >> 6;
  if (PNS){
    for (int i = t; i < 1024; i += 256) hsh[i] = hs[i];
    __syncthreads();
  }
  int row = blockIdx.x * 4 + wv;
  const float4* rp = (const float4*)(in + (size_t)row * DD);
  float4 v[4];
  float ss = 0.f;
  #pragma unroll
  for (int j = 0; j < 4; j++){
    float4 a = rp[j*64 + l];
    if (RND){ a.x = rnd_bf(a.x); a.y = rnd_bf(a.y); a.z = rnd_bf(a.z); a.w = rnd_bf(a.w); }
    v[j] = a;
    ss += a.x*a.x + a.y*a.y + a.z*a.z + a.w*a.w;
  }
  #pragma unroll
  for (int d = 1; d < 64; d <<= 1) ss += __shfl_xor(ss, d);
  float inv = 1.f / (sqrtf(ss) + 1e-8f);
  float dot = 0.f;
  ushort4* op = (ushort4*)(o + (size_t)row * DD);
  #pragma unroll
  for (int j = 0; j < 4; j++){
    ushort4 r;
    r.x = f2bf(v[j].x * inv); r.y = f2bf(v[j].y * inv);
    r.z = f2bf(v[j].z * inv); r.w = f2bf(v[j].w * inv);
    op[j*64 + l] = r;
    if (PNS){
      int c0 = (j*64 + l)*4;
      dot += hsh[c0]*bf2f(r.x) + hsh[c0+1]*bf2f(r.y)
           + hsh[c0+2]*bf2f(r.z) + hsh[c0+3]*bf2f(r.w);
    }
  }
  if (PNS){
    #pragma unroll
    for (int d = 1; d < 64; d <<= 1) dot += __shfl_xor(dot, d);
    if (l == 0){
      float pns = dot * (1.f / 8192.f);
      pr[wv*2] = pns; pr[wv*2 + 1] = pns*pns;
    }
    __syncthreads();
    if (t == 0){
      atomicAdd(ns + 0, pr[0] + pr[2] + pr[4] + pr[6]);
      atomicAdd(ns + 1, pr[1] + pr[3] + pr[5] + pr[7]);
    }
  }
}

__global__ __launch_bounds__(256) void k_wnorm(const float* __restrict__ w_,
                                               float* __restrict__ inv_w){
  int t = threadIdx.x, l = t & 63, wv = t >> 6;
  int row = blockIdx.x * 4 + wv;
  const float4* wp = (const float4*)(w_ + (size_t)row * DD);
  float sw = 0.f;
  #pragma unroll
  for (int j = 0; j < 4; j++){
    float4 c = wp[j*64 + l];
    float c0 = rnd_bf(c.x), c1 = rnd_bf(c.y), c2 = rnd_bf(c.z), c3 = rnd_bf(c.w);
    sw += c0*c0 + c1*c1 + c2*c2 + c3*c3;
  }
  #pragma unroll
  for (int d = 1; d < 64; d <<= 1) sw += __shfl_xor(sw, d);
  if (l == 0) inv_w[row] = 1.f / (sqrtf(sw) + 1e-8f);
}

__global__ __launch_bounds__(256) void k_cast(const float* __restrict__ in,
                                              unsigned short* __restrict__ o){
  size_t i = (size_t)blockIdx.x * 256 + threadIdx.x;
  float4 v = ((const float4*)in)[i];
  ushort4 r;
  r.x = f2bf(v.x); r.y = f2bf(v.y); r.z = f2bf(v.z); r.w = f2bf(v.w);
  ((ushort4*)o)[i] = r;
}

__global__ __launch_bounds__(256) void k_wcnT(const float* __restrict__ w_,
    const float* __restrict__ invw, unsigned short* __restrict__ o){
  __shared__ unsigned short tile[64][65];
  int t = threadIdx.x;
  int n0b = blockIdx.x * 64, d0 = blockIdx.y * 64;
  #pragma unroll
  for (int i = 0; i < 16; i++){
    int idx = t + i*256;
    int r = idx >> 6, c = idx & 63;
    float v = w_[(size_t)(n0b + r) * DD + d0 + c];
    tile[c][r] = f2bf(rnd_bf(v) * invw[n0b + r]);
  }
  __syncthreads();
  #pragma unroll
  for (int i = 0; i < 16; i++){
    int idx = t + i*256;
    int rd = idx >> 6, cn = idx & 63;
    o[(size_t)(d0 + rd) * NNEU + n0b + cn] = tile[rd][cn];
  }
}

__global__ __launch_bounds__(256) void k_hsum(const unsigned short* __restrict__ hb,
                                              float* __restrict__ hs){
  int t = threadIdx.x; int r0 = blockIdx.x * 128;
  float s[4] = {0.f, 0.f, 0.f, 0.f};
  for (int r = 0; r < 128; r++){
    const unsigned short* row = hb + (size_t)(r0 + r) * DD;
    #pragma unroll
    for (int j = 0; j < 4; j++) s[j] += bf2f(row[j*256 + t]);
  }
  #pragma unroll
  for (int j = 0; j < 4; j++) atomicAdd(hs + j*256 + t, s[j]);
}

// ------- score GEMM core: S = H @ E_chunk^T. Optional stats, optional store -------
// grid (64, 64) per chunk.

template<bool DO_STATS>
__global__ __launch_bounds__(256, 2) void k_score(
    const unsigned short* __restrict__ A, const unsigned short* __restrict__ Bm,
    float* __restrict__ s_sum, float* __restrict__ sq_sum, float* __restrict__ cu_sum,
    unsigned short* __restrict__ Sout, int do_store)
{
  __shared__ unsigned short lds[32768];   // 64KB: 2 bufs x (A|B)
  const int t = threadIdx.x, l = t & 63, wv = t >> 6;
  const int wm = wv >> 1, wn = wv & 1;
  const int lq = l >> 4, lr = l & 15;
  int2 rm = xcd64();
  const int bx = rm.x, by = rm.y;
  const unsigned short* Ab = A  + (size_t)by * 128 * DD;
  const unsigned short* Bb = Bm + (size_t)bx * 128 * DD;
  f32x4 acc[4][4];
  #pragma unroll
  for (int m = 0; m < 4; m++)
    #pragma unroll
    for (int n = 0; n < 4; n++) acc[m][n] = (f32x4){0.f, 0.f, 0.f, 0.f};

  stage4<0>(Ab, DD, 0, lds, t);
  stage4<0>(Bb, DD, 0, lds + 8192, t);
  waitv_bar();
  int cur = 0;
  for (int ks = 0; ks < 16; ++ks){
    unsigned short* Lc = lds + cur*16384;
    if (ks + 1 < 16){
      unsigned short* Ln = lds + (cur^1)*16384;
      int k0 = (ks+1)*64;
      stage4<0>(Ab, DD, k0, Ln, t);
      stage4<0>(Bb, DD, k0, Ln + 8192, t);
    }
    #pragma unroll
    for (int kk = 0; kk < 64; kk += 32){
      s16x8 af[4], bf4[4];
      #pragma unroll
      for (int m = 0; m < 4; m++) af[m]  = frg(Lc, wm*64 + m*16 + lr, kk, lq);
      #pragma unroll
      for (int n = 0; n < 4; n++) bf4[n] = frg(Lc + 8192, wn*64 + n*16 + lr, kk, lq);
      #pragma unroll
      for (int m = 0; m < 4; m++)
        #pragma unroll
        for (int n = 0; n < 4; n++)
          acc[m][n] = mfma16(af[m], bf4[n], acc[m][n]);
    }
    waitv_bar();
    cur ^= 1;
  }

  // stash bf16 S tile in padded LDS
  unsigned short* sl = lds;                     // [128][136]
  #pragma unroll
  for (int m = 0; m < 4; m++)
  #pragma unroll
  for (int n = 0; n < 4; n++)
  #pragma unroll
  for (int r = 0; r < 4; r++){
    int rl = wm*64 + m*16 + lq*4 + r;
    int cl = wn*64 + n*16 + lr;
    sl[rl*136 + cl] = f2bf(acc[m][n][r]);
  }
  __syncthreads();

  // row-per-thread: NT vector store + stats
  int row = t >> 1, half = t & 1;
  const unsigned short* sp = &sl[row*136 + half*64];
  unsigned short* Sdst = Sout + (size_t)(by*128 + row) * NC + bx*128 + half*64;
  float s1 = 0.f, s2 = 0.f, s3 = 0.f;
  #pragma unroll
  for (int j = 0; j < 8; j++){
    u16x8 v = *(const u16x8*)(sp + j*8);
    if (do_store) __builtin_nontemporal_store(v, (u16x8*)(Sdst + j*8));
    if (DO_STATS){
      #pragma unroll
      for (int e = 0; e < 8; e++){
        float f = bf2f(v[e]);
        s1 += f; float f2 = f*f; s2 += f2; s3 += f2*f;
      }
    }
  }
  if (DO_STATS){
    s1 += __shfl_xor(s1, 1); s2 += __shfl_xor(s2, 1); s3 += __shfl_xor(s3, 1);
    if (half == 0){
      int gr = by*128 + row;
      int rep = (bx & 7) * NTOK;
      atomicAdd(s_sum + rep + gr, s1);
      atomicAdd(sq_sum + rep + gr, s2);
      atomicAdd(cu_sum + rep + gr, s3);
    }
  }
}

__global__ __launch_bounds__(256) void k_tau(const float* __restrict__ s_sum,
    const float* __restrict__ sq_sum, const float* __restrict__ tof,
    float* __restrict__ tau, float* __restrict__ rstd){
  int i = blockIdx.x * 256 + threadIdx.x;
  float ssum = 0.f, sqsum = 0.f;
  #pragma unroll
  for (int k = 0; k < NREP; k++){
    ssum  += s_sum[k*NTOK + i];
    sqsum += sq_sum[k*NTOK + i];
  }
  float mean = ssum * (1.f / 32768.f);
  float var  = sqsum * (1.f / 32768.f) - mean*mean;
  float sstd = sqrtf(fmaxf(var, 0.f)) + 1e-8f;
  tau[i]  = mean + tof[i] * sstd;
  rstd[i] = 1.f / sstd;
}

// ------- gate: XR GEMM + gate + per-token stats; P overwrites S in place -------
// grid (64, 64). S tile prefetched (NT) into idle LDS buffer during last K-step.

__global__ __launch_bounds__(256, 2) void k_gateS(
    const unsigned short* __restrict__ Xb, const unsigned short* __restrict__ Rb,
    const float* __restrict__ tau, const float* __restrict__ rstd,
    unsigned short* __restrict__ SP, int n0,
    float* __restrict__ wcostp, float* __restrict__ gmaxp, float* __restrict__ actp,
    float* __restrict__ strongp, float* __restrict__ phibp, float* __restrict__ zsump,
    float* __restrict__ z075p, float* __restrict__ z030p, float* __restrict__ glgp)
{
  __shared__ unsigned short lds[32768];  // 64KB: 2 bufs x (X|R)
  const int t = threadIdx.x, l = t & 63, wv = t >> 6;
  const int wm = wv >> 1, wn = wv & 1;
  const int lq = l >> 4, lr = l & 15;
  int2 rm = xcd64();
  const int bx = rm.x, by = rm.y;
  const unsigned short* Xp = Xb + (size_t)by * 128 * DD;
  const unsigned short* Rp = Rb + (size_t)(n0 + bx*128) * DD;
  const unsigned short* Stile = SP + (size_t)(by*128) * NC + bx*128;
  f32x4 accX[4][4];
  #pragma unroll
  for (int m = 0; m < 4; m++)
    #pragma unroll
    for (int n = 0; n < 4; n++) accX[m][n] = (f32x4){0.f,0.f,0.f,0.f};

  stage4<0>(Xp, DD, 0, lds, t);
  stage4<0>(Rp, DD, 0, lds + 8192, t);
  waitv_bar();
  int cur = 0;
  for (int ks = 0; ks < 16; ++ks){
    unsigned short* Lc = lds + cur*16384;
    if (ks + 1 < 16){
      unsigned short* Ln = lds + (cur^1)*16384;
      int k0 = (ks+1)*64;
      stage4<0>(Xp, DD, k0, Ln, t);
      stage4<0>(Rp, DD, k0, Ln + 8192, t);
    } else {
      // last K-step: NT-prefetch S tile into the idle buffer (buf0)
      stageS<2>(Stile, NC, lds, t);
    }
    #pragma unroll
    for (int kk = 0; kk < 64; kk += 32){
      s16x8 af[4], bf4[4];
      #pragma unroll
      for (int m = 0; m < 4; m++) af[m]  = frg(Lc, wm*64 + m*16 + lr, kk, lq);
      #pragma unroll
      for (int n = 0; n < 4; n++) bf4[n] = frg(Lc + 8192, wn*64 + n*16 + lr, kk, lq);
      #pragma unroll
      for (int m = 0; m < 4; m++)
        #pragma unroll
        for (int n = 0; n < 4; n++)
          accX[m][n] = mfma16(af[m], bf4[n], accX[m][n]);
    }
    waitv_bar();
    cur ^= 1;
  }
  // S now in lds[0..16384) (chunk-XOR swizzled); stash XR into buf1 with
  // the same swizzle (conflict-free scalar writes).
  unsigned short* xrl = lds + 16384;
  #pragma unroll
  for (int m = 0; m < 4; m++)
  #pragma unroll
  for (int n = 0; n < 4; n++)
  #pragma unroll
  for (int r = 0; r < 4; r++){
    int rl = wm*64 + m*16 + lq*4 + r;
    int cl = wn*64 + n*16 + lr;
    int cs = (cl >> 3) ^ (rl & 15);
    xrl[rl*128 + cs*8 + (cl & 7)] = f2bf(accX[m][n][r]);
  }
  __syncthreads();

  // row-per-thread gate + stats; S,XR from LDS; P direct NT coalesced store
  int row = t >> 1, half = t & 1;
  int gr = by*128 + row;
  float tauv = tau[gr], rs = rstd[gr];
  unsigned short* Prow = SP + (size_t)gr * NC + bx*128 + half*64;
  float wsum = 0.f, gmx = 0.f, ac = 0.f, stc = 0.f, pb = 0.f;
  float zs = 0.f, z7 = 0.f, z3 = 0.f, gl = 0.f;
  #pragma unroll
  for (int jj = 0; jj < 8; jj++){
    int g  = half*8 + jj;
    int cs = g ^ (row & 15);
    u16x8 s8 = *(const u16x8*)&lds[row*128 + cs*8];
    u16x8 x8 = *(const u16x8*)&lds[16384 + row*128 + cs*8];
    u16x8 pv;
    #pragma unroll
    for (int e = 0; e < 8; e++){
      float sc = bf2f(s8[e]);
      float xr = bf2f(x8[e]);
      float z = (sc - tauv) * rs;
      float phi = 0.5f * (1.0f + erff(z * 0.70710678118654752440f));
      float gate = (z > 0.f) ? z * phi : 0.f;
      wsum += gate; gmx = fmaxf(gmx, gate);
      if (gate > 0.5f) stc += 1.f;
      if (fabsf(z) > 1.6448536f) pb += 1.f;           // == (phi>0.95 | phi<0.05)
      if (z > 0.f){ ac += 1.f; zs += z; if (z < 0.75f) z7 += 1.f; if (z < 0.3f) z3 += 1.f; }
      gl += gate * __logf(gate + 1e-8f);
      pv[e] = f2bf(rnd_bf(gate) * xr);
    }
    __builtin_nontemporal_store(pv, (u16x8*)(Prow + jj*8));
  }
  // pair-combine and emit into replicated slot (bx&7)
  wsum += __shfl_xor(wsum, 1); gmx = fmaxf(gmx, __shfl_xor(gmx, 1));
  ac   += __shfl_xor(ac, 1);   stc += __shfl_xor(stc, 1);
  pb   += __shfl_xor(pb, 1);   zs  += __shfl_xor(zs, 1);
  z7   += __shfl_xor(z7, 1);   z3  += __shfl_xor(z3, 1);
  gl   += __shfl_xor(gl, 1);
  if (half == 0){
    int rep = (bx & 7) * NTOK;
    atomicAdd(wcostp + rep + gr, wsum);
    atomicMax((int*)(gmaxp + rep + gr), __float_as_int(gmx));
    atomicAdd(actp + rep + gr, ac);
    atomicAdd(strongp + rep + gr, stc);
    atomicAdd(phibp + rep + gr, pb);
    atomicAdd(zsump + rep + gr, zs);
    atomicAdd(z075p + rep + gr, z7);
    atomicAdd(z030p + rep + gr, z3);
    atomicAdd(glgp + rep + gr, gl);
  }
}

// combine replicated wcost -> wc_comb
__global__ __launch_bounds__(256) void k_redw(const float* __restrict__ wcostp,
                                              float* __restrict__ wc){
  int i = blockIdx.x * 256 + threadIdx.x;
  float s = 0.f;
  #pragma unroll
  for (int k = 0; k < NREP; k++) s += wcostp[k*NTOK + i];
  wc[i] = s;
}

// ---------------- output GEMM: out (+)= P @ wcnT^T; last chunk applies /den ----------------
// grid (8, 64).

__global__ __launch_bounds__(256, 2) void k_out_gemm(
    const unsigned short* __restrict__ Pm, const unsigned short* __restrict__ Bt,
    float* __restrict__ outp, const float* __restrict__ wcost, int accum, int fin)
{
  __shared__ unsigned short lds[32768];   // 64KB: 2 bufs
  const int t = threadIdx.x, l = t & 63, wv = t >> 6;
  const int wm = wv >> 1, wn = wv & 1;
  const int lq = l >> 4, lr = l & 15;
  const int bx = blockIdx.x, by = blockIdx.y;
  const unsigned short* Ab = Pm + (size_t)by * 128 * NC;
  const unsigned short* Bb = Bt + (size_t)bx * 128 * NNEU;   // n-offset folded by caller
  f32x4 acc[4][4];
  #pragma unroll
  for (int m = 0; m < 4; m++)
    #pragma unroll
    for (int n = 0; n < 4; n++) acc[m][n] = (f32x4){0.f,0.f,0.f,0.f};

  const int NT = NC / 64;
  stage4<2>(Ab, NC, 0, lds, t);
  stage4<0>(Bb, NNEU, 0, lds + 8192, t);
  waitv_bar();
  int cur = 0;
  for (int ks = 0; ks < NT; ++ks){
    unsigned short* Lc = lds + cur*16384;
    if (ks + 1 < NT){
      unsigned short* Ln = lds + (cur^1)*16384;
      int k0 = (ks+1)*64;
      stage4<2>(Ab, NC, k0, Ln, t);
      stage4<0>(Bb, NNEU, k0, Ln + 8192, t);
    }
    #pragma unroll
    for (int kk = 0; kk < 64; kk += 32){
      s16x8 af[4], bf4[4];
      #pragma unroll
      for (int m = 0; m < 4; m++) af[m]  = frg(Lc, wm*64 + m*16 + lr, kk, lq);
      #pragma unroll
      for (int n = 0; n < 4; n++) bf4[n] = frg(Lc + 8192, wn*64 + n*16 + lr, kk, lq);
      #pragma unroll
      for (int m = 0; m < 4; m++)
        #pragma unroll
        for (int n = 0; n < 4; n++)
          acc[m][n] = mfma16(af[m], bf4[n], acc[m][n]);
    }
    waitv_bar();
    cur ^= 1;
  }
  #pragma unroll
  for (int m = 0; m < 4; m++)
  #pragma unroll
  for (int r = 0; r < 4; r++){
    int gr = by*128 + wm*64 + m*16 + lq*4 + r;
    float den = fin ? fmaxf(wcost[gr], 1.f) : 1.f;
    #pragma unroll
    for (int n = 0; n < 4; n++){
      int dc = bx*128 + wn*64 + n*16 + lr;
      float* o = outp + (size_t)gr * DD + dc;
      float v = acc[m][n][r];
      if (accum) v += *o;
      if (fin)   v = rnd_bf(v / den);
      *o = v;
    }
  }
}

// ---------------- finalize ----------------

__global__ __launch_bounds__(1024) void k_final(
    const float* __restrict__ s_sum, const float* __restrict__ sq_sum,
    const float* __restrict__ cu_sum, const float* __restrict__ tof,
    const float* __restrict__ wcostp, const float* __restrict__ gmaxp,
    const float* __restrict__ actp, const float* __restrict__ strongp,
    const float* __restrict__ phibp, const float* __restrict__ zsump,
    const float* __restrict__ z075p, const float* __restrict__ z030p,
    const float* __restrict__ glgp, const float* __restrict__ ns,
    float* __restrict__ out)
{
  int tid = threadIdx.x;
  float s0=0,s1=0,s2=0,s3=0,s4=0,s5=0,s6=0,s7=0,s8=0;
  for (int i = tid; i < NTOK; i += 1024){
    float ssum=0, sqsum=0, cusum=0, wc=0, gmax=0, ac=0, stc=0, pb=0, zsv=0, z7=0, z3=0, glv=0;
    #pragma unroll
    for (int k = 0; k < NREP; k++){
      int o = k*NTOK + i;
      ssum += s_sum[o]; sqsum += sq_sum[o]; cusum += cu_sum[o];
      wc += wcostp[o]; gmax = fmaxf(gmax, gmaxp[o]);
      ac += actp[o]; stc += strongp[o]; pb += phibp[o];
      zsv += zsump[o]; z7 += z075p[o]; z3 += z030p[o]; glv += glgp[o];
    }
    float mean = ssum * (1.f / 32768.f);
    float var  = sqsum * (1.f / 32768.f) - mean*mean;
    float sstd = sqrtf(fmaxf(var, 0.f)) + 1e-8f;
    float tauv = mean + tof[i] * sstd;
    out[OUT_ACT + i]    = ac * (1.f / 32768.f);
    out[OUT_GMAX + i]   = gmax;
    out[OUT_STRONG + i] = stc * (1.f / 32768.f);
    out[OUT_PHIB + i]   = pb * (1.f / 32768.f);
    out[OUT_ZMEAN + i]  = zsv / (ac + 1e-8f);
    float c3 = cusum * (1.f / 32768.f) - 3.f*mean*sstd*sstd - mean*mean*mean;
    float skew = c3 / (sstd*sstd*sstd + 1e-8f);
    float gse = wc + 1e-8f;
    float ent = -glv / gse + logf(gse);
    s0 += sstd; s1 += wc; s2 += ac; s3 += ac*ac; s4 += tauv;
    s5 += z7 / (ac + 1e-8f); s6 += z3 / (ac + 1e-8f); s7 += skew; s8 += ent;
  }
  __shared__ float rb[16][9];
  int lane = tid & 63, wid = tid >> 6;
  #pragma unroll
  for (int d = 1; d < 64; d <<= 1){
    s0 += __shfl_xor(s0,d); s1 += __shfl_xor(s1,d); s2 += __shfl_xor(s2,d);
    s3 += __shfl_xor(s3,d); s4 += __shfl_xor(s4,d); s5 += __shfl_xor(s5,d);
    s6 += __shfl_xor(s6,d); s7 += __shfl_xor(s7,d); s8 += __shfl_xor(s8,d);
  }
  if (lane == 0){
    rb[wid][0]=s0; rb[wid][1]=s1; rb[wid][2]=s2; rb[wid][3]=s3; rb[wid][4]=s4;
    rb[wid][5]=s5; rb[wid][6]=s6; rb[wid][7]=s7; rb[wid][8]=s8;
  }
  __syncthreads();
  if (tid == 0){
    float S[9];
    for (int k = 0; k < 9; k++){ float a = 0.f; for (int w2 = 0; w2 < 16; w2++) a += rb[w2][k]; S[k] = a; }
    const float inv = 1.f / 8192.f;
    float act_mean = S[2] * inv;
    out[OUT_SSTD] = S[0] * inv;
    out[OUT_ES]   = S[1] * inv;
    out[OUT_ANM]  = act_mean;
    out[OUT_ASTD] = sqrtf(fmaxf(S[3]*inv - act_mean*act_mean, 0.f));
    out[OUT_TAUM] = S[4] * inv;
    out[OUT_Z75]  = S[5] * inv;
    out[OUT_Z30]  = S[6] * inv;
    out[OUT_SKEW] = S[7] * inv;
    out[OUT_ENT]  = S[8] * inv;
    float ms = ns[0] * (1.f / 32768.f);
    float vs = ns[1] * (1.f / 32768.f) - ms*ms;
    out[OUT_SLB] = vs / (ms*ms + vs + 0.01f);
  }
}

// ---------------- launch ----------------

extern "C" void kernel_launch(void* const* d_in, const int* in_sizes, int n_in,
                              void* d_out, int out_size, void* d_ws, size_t ws_size,
                              hipStream_t stream)
{
  (void)in_sizes; (void)n_in; (void)out_size;
  const float* x   = (const float*)d_in[0];
  const float* h   = (const float*)d_in[1];
  const float* emb = (const float*)d_in[2];
  const float* tof = (const float*)d_in[3];
  const float* wr  = (const float*)d_in[4];
  const float* ww  = (const float*)d_in[5];
  float* out = (float*)d_out;
  char* ws = (char*)d_ws;

  size_t off = 0;
  auto get = [&](size_t n){ size_t o = off; off += (n + 255) & ~(size_t)255; return o; };
  unsigned short* rcn_bf = (unsigned short*)(ws + get((size_t)NNEU*DD*2));
  unsigned short* emb_bf = (unsigned short*)(ws + get((size_t)NNEU*DD*2));
  unsigned short* wcnT   = (unsigned short*)(ws + get((size_t)DD*NNEU*2));
  unsigned short* h_bf   = (unsigned short*)(ws + get((size_t)NTOK*DD*2));
  unsigned short* x_bf   = (unsigned short*)(ws + get((size_t)NTOK*DD*2));
  float* inv_w   = (float*)(ws + get(NNEU*4));
  float* tau     = (float*)(ws + get(NTOK*4));
  float* rstd    = (float*)(ws + get(NTOK*4));
  float* wc_comb = (float*)(ws + get(NTOK*4));
  size_t zoff = off;
  float* hsum   = (float*)(ws + get(DD*4));
  float* s_sum  = (float*)(ws + get(NREP*NTOK*4));
  float* sq_sum = (float*)(ws + get(NREP*NTOK*4));
  float* cu_sum = (float*)(ws + get(NREP*NTOK*4));
  float* wcost  = (float*)(ws + get(NREP*NTOK*4));
  float* gmax   = (float*)(ws + get(NREP*NTOK*4));
  float* act    = (float*)(ws + get(NREP*NTOK*4));
  float* strong = (float*)(ws + get(NREP*NTOK*4));
  float* phib   = (float*)(ws + get(NREP*NTOK*4));
  float* zsum   = (float*)(ws + get(NREP*NTOK*4));
  float* z075   = (float*)(ws + get(NREP*NTOK*4));
  float* z030   = (float*)(ws + get(NREP*NTOK*4));
  float* glg    = (float*)(ws + get(NREP*NTOK*4));
  float* ns     = (float*)(ws + get(256));
  size_t zlen = off - zoff;

  const size_t szS = (size_t)NTOK * NC * 2;   // 134.2 MB per chunk
  size_t poff = (off + 4095) & ~(size_t)4095;
  size_t avail = ws_size > poff ? ws_size - poff : 0;
  int kst = (int)(avail / szS);
  if (kst > 4) kst = 4;
  if (kst < 1) kst = 1;
  unsigned short* Sb = (unsigned short*)(ws + poff);

  hipMemsetAsync(ws + zoff, 0, zlen, stream);

  dim3 b256(256);
  dim3 gC(64, 64);   // per-chunk GEMM grid
  k_cast<<<dim3(NTOK*DD/4/256), b256, 0, stream>>>(h, h_bf);
  k_cast<<<dim3(NTOK*DD/4/256), b256, 0, stream>>>(x, x_bf);
  k_hsum<<<dim3(NTOK/128), b256, 0, stream>>>(h_bf, hsum);
  k_rncast<0,1><<<dim3(NNEU/4), b256, 0, stream>>>(emb, emb_bf, hsum, ns);
  k_rncast<1,0><<<dim3(NNEU/4), b256, 0, stream>>>(wr, rcn_bf, nullptr, nullptr);
  k_wnorm<<<dim3(NNEU/4), b256, 0, stream>>>(ww, inv_w);

  // phase 1: score stats over all chunks; store S for first kst chunks
  for (int c = 0; c < 4; ++c){
    unsigned short* slot = Sb + (size_t)(c < kst ? c : 0) * NTOK * NC;
    k_score<true><<<gC, b256, 0, stream>>>(h_bf, emb_bf + (size_t)c*NC*DD,
        s_sum, sq_sum, cu_sum, slot, c < kst ? 1 : 0);
  }
  k_tau<<<dim3(NTOK/256), b256, 0, stream>>>(s_sum, sq_sum, tof, tau, rstd);
  k_wcnT<<<dim3(NNEU/64, DD/64), b256, 0, stream>>>(ww, inv_w, wcnT);

  // phase 2: per chunk: [recompute S] -> gate -> out
  for (int c = 0; c < 4; ++c){
    int slot_i = (c < kst) ? c : (c % kst);
    unsigned short* slot = Sb + (size_t)slot_i * NTOK * NC;
    if (c >= kst){
      k_score<false><<<gC, b256, 0, stream>>>(h_bf, emb_bf + (size_t)c*NC*DD,
          nullptr, nullptr, nullptr, slot, 1);
    }
    k_gateS<<<gC, b256, 0, stream>>>(x_bf, rcn_bf, tau, rstd, slot, c*NC,
        wcost, gmax, act, strong, phib, zsum, z075, z030, glg);
    if (c == 3) k_redw<<<dim3(NTOK/256), b256, 0, stream>>>(wcost, wc_comb);
    k_out_gemm<<<dim3(DD/128, NTOK/128), b256, 0, stream>>>(slot, wcnT + (size_t)c*NC,
        out, wc_comb, c > 0 ? 1 : 0, c == 3 ? 1 : 0);
  }
  k_final<<<dim3(1), dim3(1024), 0, stream>>>(s_sum, sq_sum, cu_sum, tof, wcost, gmax,
      act, strong, phib, zsum, z075, z030, glg, ns, out);
}

// Round 14
// 3896.532 us; speedup vs baseline: 1.1380x; 1.1380x over previous
//
#include <hip/hip_runtime.h>

#define DEV __device__ __forceinline__

typedef __attribute__((ext_vector_type(4))) float f32x4;
typedef __attribute__((ext_vector_type(8))) short s16x8;
typedef __attribute__((ext_vector_type(8))) unsigned short u16x8;

static const int NTOK = 8192;      // B*S
static const int DD   = 1024;      // D
static const int NNEU = 32768;     // N
static const int NC   = 8192;      // chunk width (4 chunks)
static const int NREP = 8;         // stat replication (contention fix)

// output layout (floats)
static const int OUT_ACT    = 8388608;
static const int OUT_GMAX   = 8396800;
static const int OUT_SLB    = 8404992;
static const int OUT_SSTD   = 8404993;
static const int OUT_ES     = 8404994;
static const int OUT_ANM    = 8404995;
static const int OUT_STRONG = 8404996;
static const int OUT_PHIB   = 8413188;
static const int OUT_ZMEAN  = 8421380;
static const int OUT_TAUM   = 8429572;
static const int OUT_Z75    = 8429573;
static const int OUT_Z30    = 8429574;
static const int OUT_SKEW   = 8429575;
static const int OUT_ASTD   = 8429576;
static const int OUT_ENT    = 8429577;

DEV unsigned short f2bf(float f){
  unsigned u = __float_as_uint(f);
  u += 0x7fffu + ((u >> 16) & 1u);
  return (unsigned short)(u >> 16);
}
DEV float bf2f(unsigned short h){ return __uint_as_float(((unsigned)h) << 16); }
DEV float rnd_bf(float f){ return bf2f(f2bf(f)); }

template<int AUX>
DEV void gl_lds16(const void* g, void* l){
  __builtin_amdgcn_global_load_lds(
      (const __attribute__((address_space(1))) unsigned int*)g,
      (__attribute__((address_space(3))) unsigned int*)l, 16, 0, AUX);
}

DEV f32x4 mfma16(s16x8 a, s16x8 b, f32x4 c){
  return __builtin_amdgcn_mfma_f32_16x16x32_bf16(a, b, c, 0, 0, 0);
}

// stage one 128x64 bf16 tile (16KB): XOR-swizzled source, linear LDS dest.
template<int AUX>
DEV void stage4(const unsigned short* __restrict__ G, size_t ld, int k0,
                unsigned short* L, int t){
  #pragma unroll
  for (int i = 0; i < 4; i++){
    int ch = i*256 + t;
    int row = ch >> 3, c = ch & 7;
    int cs = c ^ (row & 7);
    int wb = (i*256 + (t & 192)) * 16;
    gl_lds16<AUX>(G + (size_t)row * ld + k0 + cs*8, (char*)L + wb);
  }
}

// stage one 128x128 bf16 tile (32KB) of S: chunk-XOR swizzle c^(row&15)
DEV void stageS(const unsigned short* __restrict__ S0, size_t ldS,
                unsigned short* L, int t){
  #pragma unroll
  for (int i = 0; i < 8; i++){
    int ch = i*256 + t;
    int row = ch >> 4, c = ch & 15;
    int cs = c ^ (row & 15);
    int wb = (i*256 + (t & 192)) * 16;
    gl_lds16<0>(S0 + (size_t)row * ldS + cs*8, (char*)L + wb);
  }
}

// swizzled fragment read: logical (row R, k = kk + lq*8)
DEV s16x8 frg(const unsigned short* L, int R, int kk, int lq){
  int cc = ((kk >> 3) + lq) ^ (R & 7);
  return *(const s16x8*)((const char*)L + R*128 + cc*16);
}

DEV void waitv_bar(){
  asm volatile("s_waitcnt vmcnt(0)" ::: "memory");
  __builtin_amdgcn_s_barrier();
  __builtin_amdgcn_sched_barrier(0);
}

// 8x8-square XCD-banded remap for (64,64) grids.
DEV int2 xcd64(){
  int orig = blockIdx.y * 64 + blockIdx.x;
  int xcd = orig & 7, p = orig >> 3;
  int sqy = p >> 6, off = p & 63;
  int2 r;
  r.x = xcd*8 + (off & 7);
  r.y = sqy*8 + (off >> 3);
  return r;
}

// ---------------- preprocessing ----------------

template<int RND, int PNS>
__global__ __launch_bounds__(256) void k_rncast(const float* __restrict__ in,
    unsigned short* __restrict__ o, const float* __restrict__ hs,
    float* __restrict__ ns){
  __shared__ float hsh[1024];
  __shared__ float pr[8];
  int t = threadIdx.x, l = t & 63, wv = t >> 6;
  if (PNS){
    for (int i = t; i < 1024; i += 256) hsh[i] = hs[i];
    __syncthreads();
  }
  int row = blockIdx.x * 4 + wv;
  const float4* rp = (const float4*)(in + (size_t)row * DD);
  float4 v[4];
  float ss = 0.f;
  #pragma unroll
  for (int j = 0; j < 4; j++){
    float4 a = rp[j*64 + l];
    if (RND){ a.x = rnd_bf(a.x); a.y = rnd_bf(a.y); a.z = rnd_bf(a.z); a.w = rnd_bf(a.w); }
    v[j] = a;
    ss += a.x*a.x + a.y*a.y + a.z*a.z + a.w*a.w;
  }
  #pragma unroll
  for (int d = 1; d < 64; d <<= 1) ss += __shfl_xor(ss, d);
  float inv = 1.f / (sqrtf(ss) + 1e-8f);
  float dot = 0.f;
  ushort4* op = (ushort4*)(o + (size_t)row * DD);
  #pragma unroll
  for (int j = 0; j < 4; j++){
    ushort4 r;
    r.x = f2bf(v[j].x * inv); r.y = f2bf(v[j].y * inv);
    r.z = f2bf(v[j].z * inv); r.w = f2bf(v[j].w * inv);
    op[j*64 + l] = r;
    if (PNS){
      int c0 = (j*64 + l)*4;
      dot += hsh[c0]*bf2f(r.x) + hsh[c0+1]*bf2f(r.y)
           + hsh[c0+2]*bf2f(r.z) + hsh[c0+3]*bf2f(r.w);
    }
  }
  if (PNS){
    #pragma unroll
    for (int d = 1; d < 64; d <<= 1) dot += __shfl_xor(dot, d);
    if (l == 0){
      float pns = dot * (1.f / 8192.f);
      pr[wv*2] = pns; pr[wv*2 + 1] = pns*pns;
    }
    __syncthreads();
    if (t == 0){
      atomicAdd(ns + 0, pr[0] + pr[2] + pr[4] + pr[6]);
      atomicAdd(ns + 1, pr[1] + pr[3] + pr[5] + pr[7]);
    }
  }
}

__global__ __launch_bounds__(256) void k_wnorm(const float* __restrict__ w_,
                                               float* __restrict__ inv_w){
  int t = threadIdx.x, l = t & 63, wv = t >> 6;
  int row = blockIdx.x * 4 + wv;
  const float4* wp = (const float4*)(w_ + (size_t)row * DD);
  float sw = 0.f;
  #pragma unroll
  for (int j = 0; j < 4; j++){
    float4 c = wp[j*64 + l];
    float c0 = rnd_bf(c.x), c1 = rnd_bf(c.y), c2 = rnd_bf(c.z), c3 = rnd_bf(c.w);
    sw += c0*c0 + c1*c1 + c2*c2 + c3*c3;
  }
  #pragma unroll
  for (int d = 1; d < 64; d <<= 1) sw += __shfl_xor(sw, d);
  if (l == 0) inv_w[row] = 1.f / (sqrtf(sw) + 1e-8f);
}

__global__ __launch_bounds__(256) void k_cast(const float* __restrict__ in,
                                              unsigned short* __restrict__ o){
  size_t i = (size_t)blockIdx.x * 256 + threadIdx.x;
  float4 v = ((const float4*)in)[i];
  ushort4 r;
  r.x = f2bf(v.x); r.y = f2bf(v.y); r.z = f2bf(v.z); r.w = f2bf(v.w);
  ((ushort4*)o)[i] = r;
}

__global__ __launch_bounds__(256) void k_wcnT(const float* __restrict__ w_,
    const float* __restrict__ invw, unsigned short* __restrict__ o){
  __shared__ unsigned short tile[64][65];
  int t = threadIdx.x;
  int n0b = blockIdx.x * 64, d0 = blockIdx.y * 64;
  #pragma unroll
  for (int i = 0; i < 16; i++){
    int idx = t + i*256;
    int r = idx >> 6, c = idx & 63;
    float v = w_[(size_t)(n0b + r) * DD + d0 + c];
    tile[c][r] = f2bf(rnd_bf(v) * invw[n0b + r]);
  }
  __syncthreads();
  #pragma unroll
  for (int i = 0; i < 16; i++){
    int idx = t + i*256;
    int rd = idx >> 6, cn = idx & 63;
    o[(size_t)(d0 + rd) * NNEU + n0b + cn] = tile[rd][cn];
  }
}

__global__ __launch_bounds__(256) void k_hsum(const unsigned short* __restrict__ hb,
                                              float* __restrict__ hs){
  int t = threadIdx.x; int r0 = blockIdx.x * 128;
  float s[4] = {0.f, 0.f, 0.f, 0.f};
  for (int r = 0; r < 128; r++){
    const unsigned short* row = hb + (size_t)(r0 + r) * DD;
    #pragma unroll
    for (int j = 0; j < 4; j++) s[j] += bf2f(row[j*256 + t]);
  }
  #pragma unroll
  for (int j = 0; j < 4; j++) atomicAdd(hs + j*256 + t, s[j]);
}

// ------- score GEMM core: S = H @ E_chunk^T. Optional stats, optional store -------
// grid (64, 64) per chunk.

template<bool DO_STATS>
__global__ __launch_bounds__(256, 2) void k_score(
    const unsigned short* __restrict__ A, const unsigned short* __restrict__ Bm,
    float* __restrict__ s_sum, float* __restrict__ sq_sum, float* __restrict__ cu_sum,
    unsigned short* __restrict__ Sout, int do_store)
{
  __shared__ unsigned short lds[32768];   // 64KB: 2 bufs x (A|B)
  const int t = threadIdx.x, l = t & 63, wv = t >> 6;
  const int wm = wv >> 1, wn = wv & 1;
  const int lq = l >> 4, lr = l & 15;
  int2 rm = xcd64();
  const int bx = rm.x, by = rm.y;
  const unsigned short* Ab = A  + (size_t)by * 128 * DD;
  const unsigned short* Bb = Bm + (size_t)bx * 128 * DD;
  f32x4 acc[4][4];
  #pragma unroll
  for (int m = 0; m < 4; m++)
    #pragma unroll
    for (int n = 0; n < 4; n++) acc[m][n] = (f32x4){0.f, 0.f, 0.f, 0.f};

  stage4<0>(Ab, DD, 0, lds, t);
  stage4<0>(Bb, DD, 0, lds + 8192, t);
  waitv_bar();
  int cur = 0;
  for (int ks = 0; ks < 16; ++ks){
    unsigned short* Lc = lds + cur*16384;
    if (ks + 1 < 16){
      unsigned short* Ln = lds + (cur^1)*16384;
      int k0 = (ks+1)*64;
      stage4<0>(Ab, DD, k0, Ln, t);
      stage4<0>(Bb, DD, k0, Ln + 8192, t);
    }
    #pragma unroll
    for (int kk = 0; kk < 64; kk += 32){
      s16x8 af[4], bf4[4];
      #pragma unroll
      for (int m = 0; m < 4; m++) af[m]  = frg(Lc, wm*64 + m*16 + lr, kk, lq);
      #pragma unroll
      for (int n = 0; n < 4; n++) bf4[n] = frg(Lc + 8192, wn*64 + n*16 + lr, kk, lq);
      #pragma unroll
      for (int m = 0; m < 4; m++)
        #pragma unroll
        for (int n = 0; n < 4; n++)
          acc[m][n] = mfma16(af[m], bf4[n], acc[m][n]);
    }
    waitv_bar();
    cur ^= 1;
  }

  // stash bf16 S tile in padded LDS
  unsigned short* sl = lds;                     // [128][136]
  #pragma unroll
  for (int m = 0; m < 4; m++)
  #pragma unroll
  for (int n = 0; n < 4; n++)
  #pragma unroll
  for (int r = 0; r < 4; r++){
    int rl = wm*64 + m*16 + lq*4 + r;
    int cl = wn*64 + n*16 + lr;
    sl[rl*136 + cl] = f2bf(acc[m][n][r]);
  }
  __syncthreads();

  // row-per-thread: vector store + stats
  int row = t >> 1, half = t & 1;
  const unsigned short* sp = &sl[row*136 + half*64];
  unsigned short* Sdst = Sout + (size_t)(by*128 + row) * NC + bx*128 + half*64;
  float s1 = 0.f, s2 = 0.f, s3 = 0.f;
  #pragma unroll
  for (int j = 0; j < 8; j++){
    u16x8 v = *(const u16x8*)(sp + j*8);
    if (do_store) *(u16x8*)(Sdst + j*8) = v;
    if (DO_STATS){
      #pragma unroll
      for (int e = 0; e < 8; e++){
        float f = bf2f(v[e]);
        s1 += f; float f2 = f*f; s2 += f2; s3 += f2*f;
      }
    }
  }
  if (DO_STATS){
    s1 += __shfl_xor(s1, 1); s2 += __shfl_xor(s2, 1); s3 += __shfl_xor(s3, 1);
    if (half == 0){
      int gr = by*128 + row;
      int rep = (bx & 7) * NTOK;
      atomicAdd(s_sum + rep + gr, s1);
      atomicAdd(sq_sum + rep + gr, s2);
      atomicAdd(cu_sum + rep + gr, s3);
    }
  }
}

__global__ __launch_bounds__(256) void k_tau(const float* __restrict__ s_sum,
    const float* __restrict__ sq_sum, const float* __restrict__ tof,
    float* __restrict__ tau, float* __restrict__ rstd){
  int i = blockIdx.x * 256 + threadIdx.x;
  float ssum = 0.f, sqsum = 0.f;
  #pragma unroll
  for (int k = 0; k < NREP; k++){
    ssum  += s_sum[k*NTOK + i];
    sqsum += sq_sum[k*NTOK + i];
  }
  float mean = ssum * (1.f / 32768.f);
  float var  = sqsum * (1.f / 32768.f) - mean*mean;
  float sstd = sqrtf(fmaxf(var, 0.f)) + 1e-8f;
  tau[i]  = mean + tof[i] * sstd;
  rstd[i] = 1.f / sstd;
}

// ------- gate: XR GEMM + gate + per-token stats; P overwrites S in place -------
// grid (64, 64). S tile prefetched into idle LDS buffer during last K-step.

__global__ __launch_bounds__(256, 2) void k_gateS(
    const unsigned short* __restrict__ Xb, const unsigned short* __restrict__ Rb,
    const float* __restrict__ tau, const float* __restrict__ rstd,
    unsigned short* __restrict__ SP, int n0,
    float* __restrict__ wcostp, float* __restrict__ gmaxp, float* __restrict__ actp,
    float* __restrict__ strongp, float* __restrict__ phibp, float* __restrict__ zsump,
    float* __restrict__ z075p, float* __restrict__ z030p, float* __restrict__ glgp)
{
  __shared__ unsigned short lds[32768];  // 64KB: 2 bufs x (X|R)
  const int t = threadIdx.x, l = t & 63, wv = t >> 6;
  const int wm = wv >> 1, wn = wv & 1;
  const int lq = l >> 4, lr = l & 15;
  int2 rm = xcd64();
  const int bx = rm.x, by = rm.y;
  const unsigned short* Xp = Xb + (size_t)by * 128 * DD;
  const unsigned short* Rp = Rb + (size_t)(n0 + bx*128) * DD;
  const unsigned short* Stile = SP + (size_t)(by*128) * NC + bx*128;
  f32x4 accX[4][4];
  #pragma unroll
  for (int m = 0; m < 4; m++)
    #pragma unroll
    for (int n = 0; n < 4; n++) accX[m][n] = (f32x4){0.f,0.f,0.f,0.f};

  stage4<0>(Xp, DD, 0, lds, t);
  stage4<0>(Rp, DD, 0, lds + 8192, t);
  waitv_bar();
  int cur = 0;
  for (int ks = 0; ks < 16; ++ks){
    unsigned short* Lc = lds + cur*16384;
    if (ks + 1 < 16){
      unsigned short* Ln = lds + (cur^1)*16384;
      int k0 = (ks+1)*64;
      stage4<0>(Xp, DD, k0, Ln, t);
      stage4<0>(Rp, DD, k0, Ln + 8192, t);
    } else {
      // last K-step: prefetch S tile into the idle buffer (buf0)
      stageS(Stile, NC, lds, t);
    }
    #pragma unroll
    for (int kk = 0; kk < 64; kk += 32){
      s16x8 af[4], bf4[4];
      #pragma unroll
      for (int m = 0; m < 4; m++) af[m]  = frg(Lc, wm*64 + m*16 + lr, kk, lq);
      #pragma unroll
      for (int n = 0; n < 4; n++) bf4[n] = frg(Lc + 8192, wn*64 + n*16 + lr, kk, lq);
      #pragma unroll
      for (int m = 0; m < 4; m++)
        #pragma unroll
        for (int n = 0; n < 4; n++)
          accX[m][n] = mfma16(af[m], bf4[n], accX[m][n]);
    }
    waitv_bar();
    cur ^= 1;
  }
  // S now in lds[0..16384) (chunk-XOR swizzled); stash XR into buf1 with
  // the same swizzle (conflict-free scalar writes).
  unsigned short* xrl = lds + 16384;
  #pragma unroll
  for (int m = 0; m < 4; m++)
  #pragma unroll
  for (int n = 0; n < 4; n++)
  #pragma unroll
  for (int r = 0; r < 4; r++){
    int rl = wm*64 + m*16 + lq*4 + r;
    int cl = wn*64 + n*16 + lr;
    int cs = (cl >> 3) ^ (rl & 15);
    xrl[rl*128 + cs*8 + (cl & 7)] = f2bf(accX[m][n][r]);
  }
  __syncthreads();

  // row-per-thread gate + stats; S,XR from LDS; P direct coalesced store
  int row = t >> 1, half = t & 1;
  int gr = by*128 + row;
  float tauv = tau[gr], rs = rstd[gr];
  unsigned short* Prow = SP + (size_t)gr * NC + bx*128 + half*64;
  float wsum = 0.f, gmx = 0.f, ac = 0.f, stc = 0.f, pb = 0.f;
  float zs = 0.f, z7 = 0.f, z3 = 0.f, gl = 0.f;
  #pragma unroll
  for (int jj = 0; jj < 8; jj++){
    int g  = half*8 + jj;
    int cs = g ^ (row & 15);
    u16x8 s8 = *(const u16x8*)&lds[row*128 + cs*8];
    u16x8 x8 = *(const u16x8*)&lds[16384 + row*128 + cs*8];
    u16x8 pv;
    #pragma unroll
    for (int e = 0; e < 8; e++){
      float sc = bf2f(s8[e]);
      float xr = bf2f(x8[e]);
      float z = (sc - tauv) * rs;
      float phi = 0.5f * (1.0f + erff(z * 0.70710678118654752440f));
      float gate = (z > 0.f) ? z * phi : 0.f;
      wsum += gate; gmx = fmaxf(gmx, gate);
      if (gate > 0.5f) stc += 1.f;
      if (fabsf(z) > 1.6448536f) pb += 1.f;           // == (phi>0.95 | phi<0.05)
      if (z > 0.f){ ac += 1.f; zs += z; if (z < 0.75f) z7 += 1.f; if (z < 0.3f) z3 += 1.f; }
      gl += gate * __logf(gate + 1e-8f);
      pv[e] = f2bf(rnd_bf(gate) * xr);
    }
    *(u16x8*)(Prow + jj*8) = pv;
  }
  // pair-combine and emit into replicated slot (bx&7)
  wsum += __shfl_xor(wsum, 1); gmx = fmaxf(gmx, __shfl_xor(gmx, 1));
  ac   += __shfl_xor(ac, 1);   stc += __shfl_xor(stc, 1);
  pb   += __shfl_xor(pb, 1);   zs  += __shfl_xor(zs, 1);
  z7   += __shfl_xor(z7, 1);   z3  += __shfl_xor(z3, 1);
  gl   += __shfl_xor(gl, 1);
  if (half == 0){
    int rep = (bx & 7) * NTOK;
    atomicAdd(wcostp + rep + gr, wsum);
    atomicMax((int*)(gmaxp + rep + gr), __float_as_int(gmx));
    atomicAdd(actp + rep + gr, ac);
    atomicAdd(strongp + rep + gr, stc);
    atomicAdd(phibp + rep + gr, pb);
    atomicAdd(zsump + rep + gr, zs);
    atomicAdd(z075p + rep + gr, z7);
    atomicAdd(z030p + rep + gr, z3);
    atomicAdd(glgp + rep + gr, gl);
  }
}

// combine replicated wcost -> wc_comb
__global__ __launch_bounds__(256) void k_redw(const float* __restrict__ wcostp,
                                              float* __restrict__ wc){
  int i = blockIdx.x * 256 + threadIdx.x;
  float s = 0.f;
  #pragma unroll
  for (int k = 0; k < NREP; k++) s += wcostp[k*NTOK + i];
  wc[i] = s;
}

// ---------------- output GEMM: out (+)= P @ wcnT^T; last chunk applies /den ----------------
// grid (8, 64).

__global__ __launch_bounds__(256, 2) void k_out_gemm(
    const unsigned short* __restrict__ Pm, const unsigned short* __restrict__ Bt,
    float* __restrict__ outp, const float* __restrict__ wcost, int accum, int fin)
{
  __shared__ unsigned short lds[32768];   // 64KB: 2 bufs
  const int t = threadIdx.x, l = t & 63, wv = t >> 6;
  const int wm = wv >> 1, wn = wv & 1;
  const int lq = l >> 4, lr = l & 15;
  const int bx = blockIdx.x, by = blockIdx.y;
  const unsigned short* Ab = Pm + (size_t)by * 128 * NC;
  const unsigned short* Bb = Bt + (size_t)bx * 128 * NNEU;   // n-offset folded by caller
  f32x4 acc[4][4];
  #pragma unroll
  for (int m = 0; m < 4; m++)
    #pragma unroll
    for (int n = 0; n < 4; n++) acc[m][n] = (f32x4){0.f,0.f,0.f,0.f};

  const int NT = NC / 64;
  stage4<2>(Ab, NC, 0, lds, t);
  stage4<0>(Bb, NNEU, 0, lds + 8192, t);
  waitv_bar();
  int cur = 0;
  for (int ks = 0; ks < NT; ++ks){
    unsigned short* Lc = lds + cur*16384;
    if (ks + 1 < NT){
      unsigned short* Ln = lds + (cur^1)*16384;
      int k0 = (ks+1)*64;
      stage4<2>(Ab, NC, k0, Ln, t);
      stage4<0>(Bb, NNEU, k0, Ln + 8192, t);
    }
    #pragma unroll
    for (int kk = 0; kk < 64; kk += 32){
      s16x8 af[4], bf4[4];
      #pragma unroll
      for (int m = 0; m < 4; m++) af[m]  = frg(Lc, wm*64 + m*16 + lr, kk, lq);
      #pragma unroll
      for (int n = 0; n < 4; n++) bf4[n] = frg(Lc + 8192, wn*64 + n*16 + lr, kk, lq);
      #pragma unroll
      for (int m = 0; m < 4; m++)
        #pragma unroll
        for (int n = 0; n < 4; n++)
          acc[m][n] = mfma16(af[m], bf4[n], acc[m][n]);
    }
    waitv_bar();
    cur ^= 1;
  }
  #pragma unroll
  for (int m = 0; m < 4; m++)
  #pragma unroll
  for (int r = 0; r < 4; r++){
    int gr = by*128 + wm*64 + m*16 + lq*4 + r;
    float den = fin ? fmaxf(wcost[gr], 1.f) : 1.f;
    #pragma unroll
    for (int n = 0; n < 4; n++){
      int dc = bx*128 + wn*64 + n*16 + lr;
      float* o = outp + (size_t)gr * DD + dc;
      float v = acc[m][n][r];
      if (accum) v += *o;
      if (fin)   v = rnd_bf(v / den);
      *o = v;
    }
  }
}

// ---------------- finalize ----------------

__global__ __launch_bounds__(1024) void k_final(
    const float* __restrict__ s_sum, const float* __restrict__ sq_sum,
    const float* __restrict__ cu_sum, const float* __restrict__ tof,
    const float* __restrict__ wcostp, const float* __restrict__ gmaxp,
    const float* __restrict__ actp, const float* __restrict__ strongp,
    const float* __restrict__ phibp, const float* __restrict__ zsump,
    const float* __restrict__ z075p, const float* __restrict__ z030p,
    const float* __restrict__ glgp, const float* __restrict__ ns,
    float* __restrict__ out)
{
  int tid = threadIdx.x;
  float s0=0,s1=0,s2=0,s3=0,s4=0,s5=0,s6=0,s7=0,s8=0;
  for (int i = tid; i < NTOK; i += 1024){
    float ssum=0, sqsum=0, cusum=0, wc=0, gmax=0, ac=0, stc=0, pb=0, zsv=0, z7=0, z3=0, glv=0;
    #pragma unroll
    for (int k = 0; k < NREP; k++){
      int o = k*NTOK + i;
      ssum += s_sum[o]; sqsum += sq_sum[o]; cusum += cu_sum[o];
      wc += wcostp[o]; gmax = fmaxf(gmax, gmaxp[o]);
      ac += actp[o]; stc += strongp[o]; pb += phibp[o];
      zsv += zsump[o]; z7 += z075p[o]; z3 += z030p[o]; glv += glgp[o];
    }
    float mean = ssum * (1.f / 32768.f);
    float var  = sqsum * (1.f / 32768.f) - mean*mean;
    float sstd = sqrtf(fmaxf(var, 0.f)) + 1e-8f;
    float tauv = mean + tof[i] * sstd;
    out[OUT_ACT + i]    = ac * (1.f / 32768.f);
    out[OUT_GMAX + i]   = gmax;
    out[OUT_STRONG + i] = stc * (1.f / 32768.f);
    out[OUT_PHIB + i]   = pb * (1.f / 32768.f);
    out[OUT_ZMEAN + i]  = zsv / (ac + 1e-8f);
    float c3 = cusum * (1.f / 32768.f) - 3.f*mean*sstd*sstd - mean*mean*mean;
    float skew = c3 / (sstd*sstd*sstd + 1e-8f);
    float gse = wc + 1e-8f;
    float ent = -glv / gse + logf(gse);
    s0 += sstd; s1 += wc; s2 += ac; s3 += ac*ac; s4 += tauv;
    s5 += z7 / (ac + 1e-8f); s6 += z3 / (ac + 1e-8f); s7 += skew; s8 += ent;
  }
  __shared__ float rb[16][9];
  int lane = tid & 63, wid = tid >> 6;
  #pragma unroll
  for (int d = 1; d < 64; d <<= 1){
    s0 += __shfl_xor(s0,d); s1 += __shfl_xor(s1,d); s2 += __shfl_xor(s2,d);
    s3 += __shfl_xor(s3,d); s4 += __shfl_xor(s4,d); s5 += __shfl_xor(s5,d);
    s6 += __shfl_xor(s6,d); s7 += __shfl_xor(s7,d); s8 += __shfl_xor(s8,d);
  }
  if (lane == 0){
    rb[wid][0]=s0; rb[wid][1]=s1; rb[wid][2]=s2; rb[wid][3]=s3; rb[wid][4]=s4;
    rb[wid][5]=s5; rb[wid][6]=s6; rb[wid][7]=s7; rb[wid][8]=s8;
  }
  __syncthreads();
  if (tid == 0){
    float S[9];
    for (int k = 0; k < 9; k++){ float a = 0.f; for (int w2 = 0; w2 < 16; w2++) a += rb[w2][k]; S[k] = a; }
    const float inv = 1.f / 8192.f;
    float act_mean = S[2] * inv;
    out[OUT_SSTD] = S[0] * inv;
    out[OUT_ES]   = S[1] * inv;
    out[OUT_ANM]  = act_mean;
    out[OUT_ASTD] = sqrtf(fmaxf(S[3]*inv - act_mean*act_mean, 0.f));
    out[OUT_TAUM] = S[4] * inv;
    out[OUT_Z75]  = S[5] * inv;
    out[OUT_Z30]  = S[6] * inv;
    out[OUT_SKEW] = S[7] * inv;
    out[OUT_ENT]  = S[8] * inv;
    float ms = ns[0] * (1.f / 32768.f);
    float vs = ns[1] * (1.f / 32768.f) - ms*ms;
    out[OUT_SLB] = vs / (ms*ms + vs + 0.01f);
  }
}

// ---------------- launch ----------------

extern "C" void kernel_launch(void* const* d_in, const int* in_sizes, int n_in,
                              void* d_out, int out_size, void* d_ws, size_t ws_size,
                              hipStream_t stream)
{
  (void)in_sizes; (void)n_in; (void)out_size;
  const float* x   = (const float*)d_in[0];
  const float* h   = (const float*)d_in[1];
  const float* emb = (const float*)d_in[2];
  const float* tof = (const float*)d_in[3];
  const float* wr  = (const float*)d_in[4];
  const float* ww  = (const float*)d_in[5];
  float* out = (float*)d_out;
  char* ws = (char*)d_ws;

  size_t off = 0;
  auto get = [&](size_t n){ size_t o = off; off += (n + 255) & ~(size_t)255; return o; };
  unsigned short* rcn_bf = (unsigned short*)(ws + get((size_t)NNEU*DD*2));
  unsigned short* emb_bf = (unsigned short*)(ws + get((size_t)NNEU*DD*2));
  unsigned short* wcnT   = (unsigned short*)(ws + get((size_t)DD*NNEU*2));
  unsigned short* h_bf   = (unsigned short*)(ws + get((size_t)NTOK*DD*2));
  unsigned short* x_bf   = (unsigned short*)(ws + get((size_t)NTOK*DD*2));
  float* inv_w   = (float*)(ws + get(NNEU*4));
  float* tau     = (float*)(ws + get(NTOK*4));
  float* rstd    = (float*)(ws + get(NTOK*4));
  float* wc_comb = (float*)(ws + get(NTOK*4));
  size_t zoff = off;
  float* hsum   = (float*)(ws + get(DD*4));
  float* s_sum  = (float*)(ws + get(NREP*NTOK*4));
  float* sq_sum = (float*)(ws + get(NREP*NTOK*4));
  float* cu_sum = (float*)(ws + get(NREP*NTOK*4));
  float* wcost  = (float*)(ws + get(NREP*NTOK*4));
  float* gmax   = (float*)(ws + get(NREP*NTOK*4));
  float* act    = (float*)(ws + get(NREP*NTOK*4));
  float* strong = (float*)(ws + get(NREP*NTOK*4));
  float* phib   = (float*)(ws + get(NREP*NTOK*4));
  float* zsum   = (float*)(ws + get(NREP*NTOK*4));
  float* z075   = (float*)(ws + get(NREP*NTOK*4));
  float* z030   = (float*)(ws + get(NREP*NTOK*4));
  float* glg    = (float*)(ws + get(NREP*NTOK*4));
  float* ns     = (float*)(ws + get(256));
  size_t zlen = off - zoff;

  const size_t szS = (size_t)NTOK * NC * 2;   // 134.2 MB per chunk
  size_t poff = (off + 4095) & ~(size_t)4095;
  size_t avail = ws_size > poff ? ws_size - poff : 0;
  int kst = (int)(avail / szS);
  if (kst > 4) kst = 4;
  if (kst < 1) kst = 1;
  unsigned short* Sb = (unsigned short*)(ws + poff);

  hipMemsetAsync(ws + zoff, 0, zlen, stream);

  dim3 b256(256);
  dim3 gC(64, 64);   // per-chunk GEMM grid
  k_cast<<<dim3(NTOK*DD/4/256), b256, 0, stream>>>(h, h_bf);
  k_cast<<<dim3(NTOK*DD/4/256), b256, 0, stream>>>(x, x_bf);
  k_hsum<<<dim3(NTOK/128), b256, 0, stream>>>(h_bf, hsum);
  k_rncast<0,1><<<dim3(NNEU/4), b256, 0, stream>>>(emb, emb_bf, hsum, ns);
  k_rncast<1,0><<<dim3(NNEU/4), b256, 0, stream>>>(wr, rcn_bf, nullptr, nullptr);
  k_wnorm<<<dim3(NNEU/4), b256, 0, stream>>>(ww, inv_w);

  // phase 1: score stats over all chunks; store S for first kst chunks
  for (int c = 0; c < 4; ++c){
    unsigned short* slot = Sb + (size_t)(c < kst ? c : 0) * NTOK * NC;
    k_score<true><<<gC, b256, 0, stream>>>(h_bf, emb_bf + (size_t)c*NC*DD,
        s_sum, sq_sum, cu_sum, slot, c < kst ? 1 : 0);
  }
  k_tau<<<dim3(NTOK/256), b256, 0, stream>>>(s_sum, sq_sum, tof, tau, rstd);
  k_wcnT<<<dim3(NNEU/64, DD/64), b256, 0, stream>>>(ww, inv_w, wcnT);

  // phase 2: per chunk: [recompute S] -> gate -> out
  for (int c = 0; c < 4; ++c){
    int slot_i = (c < kst) ? c : (c % kst);
    unsigned short* slot = Sb + (size_t)slot_i * NTOK * NC;
    if (c >= kst){
      k_score<false><<<gC, b256, 0, stream>>>(h_bf, emb_bf + (size_t)c*NC*DD,
          nullptr, nullptr, nullptr, slot, 1);
    }
    k_gateS<<<gC, b256, 0, stream>>>(x_bf, rcn_bf, tau, rstd, slot, c*NC,
        wcost, gmax, act, strong, phib, zsum, z075, z030, glg);
    if (c == 3) k_redw<<<dim3(NTOK/256), b256, 0, stream>>>(wcost, wc_comb);
    k_out_gemm<<<dim3(DD/128, NTOK/128), b256, 0, stream>>>(slot, wcnT + (size_t)c*NC,
        out, wc_comb, c > 0 ? 1 : 0, c == 3 ? 1 : 0);
  }
  k_final<<<dim3(1), dim3(1024), 0, stream>>>(s_sum, sq_sum, cu_sum, tof, wcost, gmax,
      act, strong, phib, zsum, z075, z030, glg, ns, out);
}

// Round 15
// 3776.356 us; speedup vs baseline: 1.1742x; 1.0318x over previous
//
#include <hip/hip_runtime.h>

#define DEV __device__ __forceinline__

typedef __attribute__((ext_vector_type(4))) float f32x4;
typedef __attribute__((ext_vector_type(8))) short s16x8;
typedef __attribute__((ext_vector_type(8))) unsigned short u16x8;

static const int NTOK = 8192;      // B*S
static const int DD   = 1024;      // D
static const int NNEU = 32768;     // N
static const int NC   = 8192;      // chunk width (4 chunks)
static const int NREP = 8;         // stat replication (contention fix)

// output layout (floats)
static const int OUT_ACT    = 8388608;
static const int OUT_GMAX   = 8396800;
static const int OUT_SLB    = 8404992;
static const int OUT_SSTD   = 8404993;
static const int OUT_ES     = 8404994;
static const int OUT_ANM    = 8404995;
static const int OUT_STRONG = 8404996;
static const int OUT_PHIB   = 8413188;
static const int OUT_ZMEAN  = 8421380;
static const int OUT_TAUM   = 8429572;
static const int OUT_Z75    = 8429573;
static const int OUT_Z30    = 8429574;
static const int OUT_SKEW   = 8429575;
static const int OUT_ASTD   = 8429576;
static const int OUT_ENT    = 8429577;

DEV unsigned short f2bf(float f){
  unsigned u = __float_as_uint(f);
  u += 0x7fffu + ((u >> 16) & 1u);
  return (unsigned short)(u >> 16);
}
DEV float bf2f(unsigned short h){ return __uint_as_float(((unsigned)h) << 16); }
DEV float rnd_bf(float f){ return bf2f(f2bf(f)); }

template<int AUX>
DEV void gl_lds16(const void* g, void* l){
  __builtin_amdgcn_global_load_lds(
      (const __attribute__((address_space(1))) unsigned int*)g,
      (__attribute__((address_space(3))) unsigned int*)l, 16, 0, AUX);
}

DEV f32x4 mfma16(s16x8 a, s16x8 b, f32x4 c){
  return __builtin_amdgcn_mfma_f32_16x16x32_bf16(a, b, c, 0, 0, 0);
}

// stage one 128x64 bf16 tile (16KB): XOR-swizzled source, linear LDS dest.
template<int AUX>
DEV void stage4(const unsigned short* __restrict__ G, size_t ld, int k0,
                unsigned short* L, int t){
  #pragma unroll
  for (int i = 0; i < 4; i++){
    int ch = i*256 + t;
    int row = ch >> 3, c = ch & 7;
    int cs = c ^ (row & 7);
    int wb = (i*256 + (t & 192)) * 16;
    gl_lds16<AUX>(G + (size_t)row * ld + k0 + cs*8, (char*)L + wb);
  }
}

// stage one 128x128 bf16 tile (32KB) of S: chunk-XOR swizzle c^(row&15)
DEV void stageS(const unsigned short* __restrict__ S0, size_t ldS,
                unsigned short* L, int t){
  #pragma unroll
  for (int i = 0; i < 8; i++){
    int ch = i*256 + t;
    int row = ch >> 4, c = ch & 15;
    int cs = c ^ (row & 15);
    int wb = (i*256 + (t & 192)) * 16;
    gl_lds16<0>(S0 + (size_t)row * ldS + cs*8, (char*)L + wb);
  }
}

// swizzled fragment read: logical (row R, k = kk + lq*8)
DEV s16x8 frg(const unsigned short* L, int R, int kk, int lq){
  int cc = ((kk >> 3) + lq) ^ (R & 7);
  return *(const s16x8*)((const char*)L + R*128 + cc*16);
}

DEV void waitv_bar(){
  asm volatile("s_waitcnt vmcnt(0)" ::: "memory");
  __builtin_amdgcn_s_barrier();
  __builtin_amdgcn_sched_barrier(0);
}

// 8x8-square XCD-banded remap for (64,64) grids.
DEV int2 xcd64(){
  int orig = blockIdx.y * 64 + blockIdx.x;
  int xcd = orig & 7, p = orig >> 3;
  int sqy = p >> 6, off = p & 63;
  int2 r;
  r.x = xcd*8 + (off & 7);
  r.y = sqy*8 + (off >> 3);
  return r;
}

// ---------------- preprocessing ----------------

template<int RND, int PNS>
__global__ __launch_bounds__(256) void k_rncast(const float* __restrict__ in,
    unsigned short* __restrict__ o, const float* __restrict__ hs,
    float* __restrict__ ns){
  __shared__ float hsh[1024];
  __shared__ float pr[8];
  int t = threadIdx.x, l = t & 63, wv = t >> 6;
  if (PNS){
    for (int i = t; i < 1024; i += 256) hsh[i] = hs[i];
    __syncthreads();
  }
  int row = blockIdx.x * 4 + wv;
  const float4* rp = (const float4*)(in + (size_t)row * DD);
  float4 v[4];
  float ss = 0.f;
  #pragma unroll
  for (int j = 0; j < 4; j++){
    float4 a = rp[j*64 + l];
    if (RND){ a.x = rnd_bf(a.x); a.y = rnd_bf(a.y); a.z = rnd_bf(a.z); a.w = rnd_bf(a.w); }
    v[j] = a;
    ss += a.x*a.x + a.y*a.y + a.z*a.z + a.w*a.w;
  }
  #pragma unroll
  for (int d = 1; d < 64; d <<= 1) ss += __shfl_xor(ss, d);
  float inv = 1.f / (sqrtf(ss) + 1e-8f);
  float dot = 0.f;
  ushort4* op = (ushort4*)(o + (size_t)row * DD);
  #pragma unroll
  for (int j = 0; j < 4; j++){
    ushort4 r;
    r.x = f2bf(v[j].x * inv); r.y = f2bf(v[j].y * inv);
    r.z = f2bf(v[j].z * inv); r.w = f2bf(v[j].w * inv);
    op[j*64 + l] = r;
    if (PNS){
      int c0 = (j*64 + l)*4;
      dot += hsh[c0]*bf2f(r.x) + hsh[c0+1]*bf2f(r.y)
           + hsh[c0+2]*bf2f(r.z) + hsh[c0+3]*bf2f(r.w);
    }
  }
  if (PNS){
    #pragma unroll
    for (int d = 1; d < 64; d <<= 1) dot += __shfl_xor(dot, d);
    if (l == 0){
      float pns = dot * (1.f / 8192.f);
      pr[wv*2] = pns; pr[wv*2 + 1] = pns*pns;
    }
    __syncthreads();
    if (t == 0){
      atomicAdd(ns + 0, pr[0] + pr[2] + pr[4] + pr[6]);
      atomicAdd(ns + 1, pr[1] + pr[3] + pr[5] + pr[7]);
    }
  }
}

__global__ __launch_bounds__(256) void k_wnorm(const float* __restrict__ w_,
                                               float* __restrict__ inv_w){
  int t = threadIdx.x, l = t & 63, wv = t >> 6;
  int row = blockIdx.x * 4 + wv;
  const float4* wp = (const float4*)(w_ + (size_t)row * DD);
  float sw = 0.f;
  #pragma unroll
  for (int j = 0; j < 4; j++){
    float4 c = wp[j*64 + l];
    float c0 = rnd_bf(c.x), c1 = rnd_bf(c.y), c2 = rnd_bf(c.z), c3 = rnd_bf(c.w);
    sw += c0*c0 + c1*c1 + c2*c2 + c3*c3;
  }
  #pragma unroll
  for (int d = 1; d < 64; d <<= 1) sw += __shfl_xor(sw, d);
  if (l == 0) inv_w[row] = 1.f / (sqrtf(sw) + 1e-8f);
}

__global__ __launch_bounds__(256) void k_cast(const float* __restrict__ in,
                                              unsigned short* __restrict__ o){
  size_t i = (size_t)blockIdx.x * 256 + threadIdx.x;
  float4 v = ((const float4*)in)[i];
  ushort4 r;
  r.x = f2bf(v.x); r.y = f2bf(v.y); r.z = f2bf(v.z); r.w = f2bf(v.w);
  ((ushort4*)o)[i] = r;
}

__global__ __launch_bounds__(256) void k_wcnT(const float* __restrict__ w_,
    const float* __restrict__ invw, unsigned short* __restrict__ o){
  __shared__ unsigned short tile[64][65];
  int t = threadIdx.x;
  int n0b = blockIdx.x * 64, d0 = blockIdx.y * 64;
  #pragma unroll
  for (int i = 0; i < 16; i++){
    int idx = t + i*256;
    int r = idx >> 6, c = idx & 63;
    float v = w_[(size_t)(n0b + r) * DD + d0 + c];
    tile[c][r] = f2bf(rnd_bf(v) * invw[n0b + r]);
  }
  __syncthreads();
  #pragma unroll
  for (int i = 0; i < 16; i++){
    int idx = t + i*256;
    int rd = idx >> 6, cn = idx & 63;
    o[(size_t)(d0 + rd) * NNEU + n0b + cn] = tile[rd][cn];
  }
}

__global__ __launch_bounds__(256) void k_hsum(const unsigned short* __restrict__ hb,
                                              float* __restrict__ hs){
  int t = threadIdx.x; int r0 = blockIdx.x * 128;
  float s[4] = {0.f, 0.f, 0.f, 0.f};
  for (int r = 0; r < 128; r++){
    const unsigned short* row = hb + (size_t)(r0 + r) * DD;
    #pragma unroll
    for (int j = 0; j < 4; j++) s[j] += bf2f(row[j*256 + t]);
  }
  #pragma unroll
  for (int j = 0; j < 4; j++) atomicAdd(hs + j*256 + t, s[j]);
}

// ------- score GEMM core: S = H @ E_chunk^T (+stats, +store). grid (64,64) -------

template<bool DO_STATS>
__global__ __launch_bounds__(256, 2) void k_score(
    const unsigned short* __restrict__ A, const unsigned short* __restrict__ Bm,
    float* __restrict__ s_sum, float* __restrict__ sq_sum, float* __restrict__ cu_sum,
    unsigned short* __restrict__ Sout, int do_store)
{
  __shared__ unsigned short lds[32768];   // 64KB: 2 bufs x (A|B)
  const int t = threadIdx.x, l = t & 63, wv = t >> 6;
  const int wm = wv >> 1, wn = wv & 1;
  const int lq = l >> 4, lr = l & 15;
  int2 rm = xcd64();
  const int bx = rm.x, by = rm.y;
  const unsigned short* Ab = A  + (size_t)by * 128 * DD;
  const unsigned short* Bb = Bm + (size_t)bx * 128 * DD;
  f32x4 acc[4][4];
  #pragma unroll
  for (int m = 0; m < 4; m++)
    #pragma unroll
    for (int n = 0; n < 4; n++) acc[m][n] = (f32x4){0.f, 0.f, 0.f, 0.f};

  stage4<0>(Ab, DD, 0, lds, t);
  stage4<0>(Bb, DD, 0, lds + 8192, t);
  waitv_bar();
  int cur = 0;
  for (int ks = 0; ks < 16; ++ks){
    unsigned short* Lc = lds + cur*16384;
    if (ks + 1 < 16){
      unsigned short* Ln = lds + (cur^1)*16384;
      int k0 = (ks+1)*64;
      stage4<0>(Ab, DD, k0, Ln, t);
      stage4<0>(Bb, DD, k0, Ln + 8192, t);
    }
    #pragma unroll
    for (int kk = 0; kk < 64; kk += 32){
      s16x8 af[4], bf4[4];
      #pragma unroll
      for (int m = 0; m < 4; m++) af[m]  = frg(Lc, wm*64 + m*16 + lr, kk, lq);
      #pragma unroll
      for (int n = 0; n < 4; n++) bf4[n] = frg(Lc + 8192, wn*64 + n*16 + lr, kk, lq);
      #pragma unroll
      for (int m = 0; m < 4; m++)
        #pragma unroll
        for (int n = 0; n < 4; n++)
          acc[m][n] = mfma16(af[m], bf4[n], acc[m][n]);
    }
    waitv_bar();
    cur ^= 1;
  }

  // stash bf16 S tile in padded LDS
  unsigned short* sl = lds;                     // [128][136]
  #pragma unroll
  for (int m = 0; m < 4; m++)
  #pragma unroll
  for (int n = 0; n < 4; n++)
  #pragma unroll
  for (int r = 0; r < 4; r++){
    int rl = wm*64 + m*16 + lq*4 + r;
    int cl = wn*64 + n*16 + lr;
    sl[rl*136 + cl] = f2bf(acc[m][n][r]);
  }
  __syncthreads();

  // row-per-thread: vector store + stats
  int row = t >> 1, half = t & 1;
  const unsigned short* sp = &sl[row*136 + half*64];
  unsigned short* Sdst = Sout + (size_t)(by*128 + row) * NC + bx*128 + half*64;
  float s1 = 0.f, s2 = 0.f, s3 = 0.f;
  #pragma unroll
  for (int j = 0; j < 8; j++){
    u16x8 v = *(const u16x8*)(sp + j*8);
    if (do_store) *(u16x8*)(Sdst + j*8) = v;
    if (DO_STATS){
      #pragma unroll
      for (int e = 0; e < 8; e++){
        float f = bf2f(v[e]);
        s1 += f; float f2 = f*f; s2 += f2; s3 += f2*f;
      }
    }
  }
  if (DO_STATS){
    s1 += __shfl_xor(s1, 1); s2 += __shfl_xor(s2, 1); s3 += __shfl_xor(s3, 1);
    if (half == 0){
      int gr = by*128 + row;
      int rep = (bx & 7) * NTOK;
      atomicAdd(s_sum + rep + gr, s1);
      atomicAdd(sq_sum + rep + gr, s2);
      atomicAdd(cu_sum + rep + gr, s3);
    }
  }
}

__global__ __launch_bounds__(256) void k_tau(const float* __restrict__ s_sum,
    const float* __restrict__ sq_sum, const float* __restrict__ tof,
    float* __restrict__ tau, float* __restrict__ rstd){
  int i = blockIdx.x * 256 + threadIdx.x;
  float ssum = 0.f, sqsum = 0.f;
  #pragma unroll
  for (int k = 0; k < NREP; k++){
    ssum  += s_sum[k*NTOK + i];
    sqsum += sq_sum[k*NTOK + i];
  }
  float mean = ssum * (1.f / 32768.f);
  float var  = sqsum * (1.f / 32768.f) - mean*mean;
  float sstd = sqrtf(fmaxf(var, 0.f)) + 1e-8f;
  tau[i]  = mean + tof[i] * sstd;
  rstd[i] = 1.f / sstd;
}

// shared gate epilogue: S in lds[0..16384) (chunk-XOR), XR in lds[16384..)
DEV void gate_epilogue(unsigned short* lds, unsigned short* SP,
    const float* tau, const float* rstd, int bx, int by, int t,
    float* wcostp, float* gmaxp, float* actp, float* strongp, float* phibp,
    float* zsump, float* z075p, float* z030p, float* glgp)
{
  int row = t >> 1, half = t & 1;
  int gr = by*128 + row;
  float tauv = tau[gr], rs = rstd[gr];
  unsigned short* Prow = SP + (size_t)gr * NC + bx*128 + half*64;
  float wsum = 0.f, gmx = 0.f, ac = 0.f, stc = 0.f, pb = 0.f;
  float zs = 0.f, z7 = 0.f, z3 = 0.f, gl = 0.f;
  #pragma unroll
  for (int jj = 0; jj < 8; jj++){
    int g  = half*8 + jj;
    int cs = g ^ (row & 15);
    u16x8 s8 = *(const u16x8*)&lds[row*128 + cs*8];
    u16x8 x8 = *(const u16x8*)&lds[16384 + row*128 + cs*8];
    u16x8 pv;
    #pragma unroll
    for (int e = 0; e < 8; e++){
      float sc = bf2f(s8[e]);
      float xr = bf2f(x8[e]);
      float z = (sc - tauv) * rs;
      float phi = 0.5f * (1.0f + erff(z * 0.70710678118654752440f));
      float gate = (z > 0.f) ? z * phi : 0.f;
      wsum += gate; gmx = fmaxf(gmx, gate);
      if (gate > 0.5f) stc += 1.f;
      if (fabsf(z) > 1.6448536f) pb += 1.f;           // == (phi>0.95 | phi<0.05)
      if (z > 0.f){ ac += 1.f; zs += z; if (z < 0.75f) z7 += 1.f; if (z < 0.3f) z3 += 1.f; }
      gl += gate * __logf(gate + 1e-8f);
      pv[e] = f2bf(rnd_bf(gate) * xr);
    }
    *(u16x8*)(Prow + jj*8) = pv;
  }
  wsum += __shfl_xor(wsum, 1); gmx = fmaxf(gmx, __shfl_xor(gmx, 1));
  ac   += __shfl_xor(ac, 1);   stc += __shfl_xor(stc, 1);
  pb   += __shfl_xor(pb, 1);   zs  += __shfl_xor(zs, 1);
  z7   += __shfl_xor(z7, 1);   z3  += __shfl_xor(z3, 1);
  gl   += __shfl_xor(gl, 1);
  if (half == 0){
    int rep = (bx & 7) * NTOK;
    atomicAdd(wcostp + rep + gr, wsum);
    atomicMax((int*)(gmaxp + rep + gr), __float_as_int(gmx));
    atomicAdd(actp + rep + gr, ac);
    atomicAdd(strongp + rep + gr, stc);
    atomicAdd(phibp + rep + gr, pb);
    atomicAdd(zsump + rep + gr, zs);
    atomicAdd(z075p + rep + gr, z7);
    atomicAdd(z030p + rep + gr, z3);
    atomicAdd(glgp + rep + gr, gl);
  }
}

// ------- gate (stored S): XR GEMM + gate; P overwrites S. grid (64,64) -------

__global__ __launch_bounds__(256, 2) void k_gateS(
    const unsigned short* __restrict__ Xb, const unsigned short* __restrict__ Rb,
    const float* __restrict__ tau, const float* __restrict__ rstd,
    unsigned short* __restrict__ SP, int n0,
    float* __restrict__ wcostp, float* __restrict__ gmaxp, float* __restrict__ actp,
    float* __restrict__ strongp, float* __restrict__ phibp, float* __restrict__ zsump,
    float* __restrict__ z075p, float* __restrict__ z030p, float* __restrict__ glgp)
{
  __shared__ unsigned short lds[32768];  // 64KB: 2 bufs x (X|R)
  const int t = threadIdx.x, l = t & 63, wv = t >> 6;
  const int wm = wv >> 1, wn = wv & 1;
  const int lq = l >> 4, lr = l & 15;
  int2 rm = xcd64();
  const int bx = rm.x, by = rm.y;
  const unsigned short* Xp = Xb + (size_t)by * 128 * DD;
  const unsigned short* Rp = Rb + (size_t)(n0 + bx*128) * DD;
  const unsigned short* Stile = SP + (size_t)(by*128) * NC + bx*128;
  f32x4 accX[4][4];
  #pragma unroll
  for (int m = 0; m < 4; m++)
    #pragma unroll
    for (int n = 0; n < 4; n++) accX[m][n] = (f32x4){0.f,0.f,0.f,0.f};

  stage4<0>(Xp, DD, 0, lds, t);
  stage4<0>(Rp, DD, 0, lds + 8192, t);
  waitv_bar();
  int cur = 0;
  for (int ks = 0; ks < 16; ++ks){
    unsigned short* Lc = lds + cur*16384;
    if (ks + 1 < 16){
      unsigned short* Ln = lds + (cur^1)*16384;
      int k0 = (ks+1)*64;
      stage4<0>(Xp, DD, k0, Ln, t);
      stage4<0>(Rp, DD, k0, Ln + 8192, t);
    } else {
      // last K-step: prefetch S tile into the idle buffer (buf0)
      stageS(Stile, NC, lds, t);
    }
    #pragma unroll
    for (int kk = 0; kk < 64; kk += 32){
      s16x8 af[4], bf4[4];
      #pragma unroll
      for (int m = 0; m < 4; m++) af[m]  = frg(Lc, wm*64 + m*16 + lr, kk, lq);
      #pragma unroll
      for (int n = 0; n < 4; n++) bf4[n] = frg(Lc + 8192, wn*64 + n*16 + lr, kk, lq);
      #pragma unroll
      for (int m = 0; m < 4; m++)
        #pragma unroll
        for (int n = 0; n < 4; n++)
          accX[m][n] = mfma16(af[m], bf4[n], accX[m][n]);
    }
    waitv_bar();
    cur ^= 1;
  }
  // S in lds[0..16384); stash XR into buf1 with the same swizzle.
  unsigned short* xrl = lds + 16384;
  #pragma unroll
  for (int m = 0; m < 4; m++)
  #pragma unroll
  for (int n = 0; n < 4; n++)
  #pragma unroll
  for (int r = 0; r < 4; r++){
    int rl = wm*64 + m*16 + lq*4 + r;
    int cl = wn*64 + n*16 + lr;
    int cs = (cl >> 3) ^ (rl & 15);
    xrl[rl*128 + cs*8 + (cl & 7)] = f2bf(accX[m][n][r]);
  }
  __syncthreads();

  gate_epilogue(lds, SP, tau, rstd, bx, by, t,
      wcostp, gmaxp, actp, strongp, phibp, zsump, z075p, z030p, glgp);
}

// ------- gate (dual GEMM): S and XR computed together; no S round-trip -------
// For chunks without stored S. grid (64,64). Ec/Rc are chunk-base pointers.

__global__ __launch_bounds__(256, 2) void k_gate_dual(
    const unsigned short* __restrict__ Hb, const unsigned short* __restrict__ Ec,
    const unsigned short* __restrict__ Xb, const unsigned short* __restrict__ Rc,
    const float* __restrict__ tau, const float* __restrict__ rstd,
    unsigned short* __restrict__ SP,
    float* __restrict__ wcostp, float* __restrict__ gmaxp, float* __restrict__ actp,
    float* __restrict__ strongp, float* __restrict__ phibp, float* __restrict__ zsump,
    float* __restrict__ z075p, float* __restrict__ z030p, float* __restrict__ glgp)
{
  __shared__ unsigned short lds[32768];  // 64KB: H|E|X|R (16KB each), single-buf
  const int t = threadIdx.x, l = t & 63, wv = t >> 6;
  const int wm = wv >> 1, wn = wv & 1;
  const int lq = l >> 4, lr = l & 15;
  int2 rm = xcd64();
  const int bx = rm.x, by = rm.y;
  const unsigned short* Hp = Hb + (size_t)by * 128 * DD;
  const unsigned short* Xp = Xb + (size_t)by * 128 * DD;
  const unsigned short* Ep = Ec + (size_t)(bx*128) * DD;
  const unsigned short* Rp = Rc + (size_t)(bx*128) * DD;
  f32x4 accS[4][4], accX[4][4];
  #pragma unroll
  for (int m = 0; m < 4; m++)
    #pragma unroll
    for (int n = 0; n < 4; n++){
      accS[m][n] = (f32x4){0.f,0.f,0.f,0.f};
      accX[m][n] = (f32x4){0.f,0.f,0.f,0.f};
    }

  for (int k0 = 0; k0 < DD; k0 += 64){
    __syncthreads();
    stage4<0>(Hp, DD, k0, lds +     0, t);
    stage4<0>(Ep, DD, k0, lds +  8192, t);
    stage4<0>(Xp, DD, k0, lds + 16384, t);
    stage4<0>(Rp, DD, k0, lds + 24576, t);
    asm volatile("s_waitcnt vmcnt(0)" ::: "memory");
    __syncthreads();
    #pragma unroll
    for (int kk = 0; kk < 64; kk += 32){
      s16x8 af[4], bf4[4];
      #pragma unroll
      for (int m = 0; m < 4; m++) af[m]  = frg(lds, wm*64 + m*16 + lr, kk, lq);
      #pragma unroll
      for (int n = 0; n < 4; n++) bf4[n] = frg(lds + 8192, wn*64 + n*16 + lr, kk, lq);
      #pragma unroll
      for (int m = 0; m < 4; m++)
        #pragma unroll
        for (int n = 0; n < 4; n++)
          accS[m][n] = mfma16(af[m], bf4[n], accS[m][n]);
      #pragma unroll
      for (int m = 0; m < 4; m++) af[m]  = frg(lds + 16384, wm*64 + m*16 + lr, kk, lq);
      #pragma unroll
      for (int n = 0; n < 4; n++) bf4[n] = frg(lds + 24576, wn*64 + n*16 + lr, kk, lq);
      #pragma unroll
      for (int m = 0; m < 4; m++)
        #pragma unroll
        for (int n = 0; n < 4; n++)
          accX[m][n] = mfma16(af[m], bf4[n], accX[m][n]);
    }
  }
  __syncthreads();
  // stash S into lds[0..16384) and XR into lds[16384..) with chunk-XOR swizzle
  #pragma unroll
  for (int m = 0; m < 4; m++)
  #pragma unroll
  for (int n = 0; n < 4; n++)
  #pragma unroll
  for (int r = 0; r < 4; r++){
    int rl = wm*64 + m*16 + lq*4 + r;
    int cl = wn*64 + n*16 + lr;
    int cs = (cl >> 3) ^ (rl & 15);
    lds[rl*128 + cs*8 + (cl & 7)]         = f2bf(accS[m][n][r]);
    lds[16384 + rl*128 + cs*8 + (cl & 7)] = f2bf(accX[m][n][r]);
  }
  __syncthreads();

  gate_epilogue(lds, SP, tau, rstd, bx, by, t,
      wcostp, gmaxp, actp, strongp, phibp, zsump, z075p, z030p, glgp);
}

// combine replicated wcost -> wc_comb
__global__ __launch_bounds__(256) void k_redw(const float* __restrict__ wcostp,
                                              float* __restrict__ wc){
  int i = blockIdx.x * 256 + threadIdx.x;
  float s = 0.f;
  #pragma unroll
  for (int k = 0; k < NREP; k++) s += wcostp[k*NTOK + i];
  wc[i] = s;
}

// ---------------- output GEMM: out (+)= P @ wcnT^T; last chunk applies /den ----------------
// grid (8, 64).

__global__ __launch_bounds__(256, 2) void k_out_gemm(
    const unsigned short* __restrict__ Pm, const unsigned short* __restrict__ Bt,
    float* __restrict__ outp, const float* __restrict__ wcost, int accum, int fin)
{
  __shared__ unsigned short lds[32768];   // 64KB: 2 bufs
  const int t = threadIdx.x, l = t & 63, wv = t >> 6;
  const int wm = wv >> 1, wn = wv & 1;
  const int lq = l >> 4, lr = l & 15;
  const int bx = blockIdx.x, by = blockIdx.y;
  const unsigned short* Ab = Pm + (size_t)by * 128 * NC;
  const unsigned short* Bb = Bt + (size_t)bx * 128 * NNEU;   // n-offset folded by caller
  f32x4 acc[4][4];
  #pragma unroll
  for (int m = 0; m < 4; m++)
    #pragma unroll
    for (int n = 0; n < 4; n++) acc[m][n] = (f32x4){0.f,0.f,0.f,0.f};

  const int NT = NC / 64;
  stage4<2>(Ab, NC, 0, lds, t);
  stage4<0>(Bb, NNEU, 0, lds + 8192, t);
  waitv_bar();
  int cur = 0;
  for (int ks = 0; ks < NT; ++ks){
    unsigned short* Lc = lds + cur*16384;
    if (ks + 1 < NT){
      unsigned short* Ln = lds + (cur^1)*16384;
      int k0 = (ks+1)*64;
      stage4<2>(Ab, NC, k0, Ln, t);
      stage4<0>(Bb, NNEU, k0, Ln + 8192, t);
    }
    #pragma unroll
    for (int kk = 0; kk < 64; kk += 32){
      s16x8 af[4], bf4[4];
      #pragma unroll
      for (int m = 0; m < 4; m++) af[m]  = frg(Lc, wm*64 + m*16 + lr, kk, lq);
      #pragma unroll
      for (int n = 0; n < 4; n++) bf4[n] = frg(Lc + 8192, wn*64 + n*16 + lr, kk, lq);
      #pragma unroll
      for (int m = 0; m < 4; m++)
        #pragma unroll
        for (int n = 0; n < 4; n++)
          acc[m][n] = mfma16(af[m], bf4[n], acc[m][n]);
    }
    waitv_bar();
    cur ^= 1;
  }
  #pragma unroll
  for (int m = 0; m < 4; m++)
  #pragma unroll
  for (int r = 0; r < 4; r++){
    int gr = by*128 + wm*64 + m*16 + lq*4 + r;
    float den = fin ? fmaxf(wcost[gr], 1.f) : 1.f;
    #pragma unroll
    for (int n = 0; n < 4; n++){
      int dc = bx*128 + wn*64 + n*16 + lr;
      float* o = outp + (size_t)gr * DD + dc;
      float v = acc[m][n][r];
      if (accum) v += *o;
      if (fin)   v = rnd_bf(v / den);
      *o = v;
    }
  }
}

// ---------------- finalize ----------------

__global__ __launch_bounds__(1024) void k_final(
    const float* __restrict__ s_sum, const float* __restrict__ sq_sum,
    const float* __restrict__ cu_sum, const float* __restrict__ tof,
    const float* __restrict__ wcostp, const float* __restrict__ gmaxp,
    const float* __restrict__ actp, const float* __restrict__ strongp,
    const float* __restrict__ phibp, const float* __restrict__ zsump,
    const float* __restrict__ z075p, const float* __restrict__ z030p,
    const float* __restrict__ glgp, const float* __restrict__ ns,
    float* __restrict__ out)
{
  int tid = threadIdx.x;
  float s0=0,s1=0,s2=0,s3=0,s4=0,s5=0,s6=0,s7=0,s8=0;
  for (int i = tid; i < NTOK; i += 1024){
    float ssum=0, sqsum=0, cusum=0, wc=0, gmax=0, ac=0, stc=0, pb=0, zsv=0, z7=0, z3=0, glv=0;
    #pragma unroll
    for (int k = 0; k < NREP; k++){
      int o = k*NTOK + i;
      ssum += s_sum[o]; sqsum += sq_sum[o]; cusum += cu_sum[o];
      wc += wcostp[o]; gmax = fmaxf(gmax, gmaxp[o]);
      ac += actp[o]; stc += strongp[o]; pb += phibp[o];
      zsv += zsump[o]; z7 += z075p[o]; z3 += z030p[o]; glv += glgp[o];
    }
    float mean = ssum * (1.f / 32768.f);
    float var  = sqsum * (1.f / 32768.f) - mean*mean;
    float sstd = sqrtf(fmaxf(var, 0.f)) + 1e-8f;
    float tauv = mean + tof[i] * sstd;
    out[OUT_ACT + i]    = ac * (1.f / 32768.f);
    out[OUT_GMAX + i]   = gmax;
    out[OUT_STRONG + i] = stc * (1.f / 32768.f);
    out[OUT_PHIB + i]   = pb * (1.f / 32768.f);
    out[OUT_ZMEAN + i]  = zsv / (ac + 1e-8f);
    float c3 = cusum * (1.f / 32768.f) - 3.f*mean*sstd*sstd - mean*mean*mean;
    float skew = c3 / (sstd*sstd*sstd + 1e-8f);
    float gse = wc + 1e-8f;
    float ent = -glv / gse + logf(gse);
    s0 += sstd; s1 += wc; s2 += ac; s3 += ac*ac; s4 += tauv;
    s5 += z7 / (ac + 1e-8f); s6 += z3 / (ac + 1e-8f); s7 += skew; s8 += ent;
  }
  __shared__ float rb[16][9];
  int lane = tid & 63, wid = tid >> 6;
  #pragma unroll
  for (int d = 1; d < 64; d <<= 1){
    s0 += __shfl_xor(s0,d); s1 += __shfl_xor(s1,d); s2 += __shfl_xor(s2,d);
    s3 += __shfl_xor(s3,d); s4 += __shfl_xor(s4,d); s5 += __shfl_xor(s5,d);
    s6 += __shfl_xor(s6,d); s7 += __shfl_xor(s7,d); s8 += __shfl_xor(s8,d);
  }
  if (lane == 0){
    rb[wid][0]=s0; rb[wid][1]=s1; rb[wid][2]=s2; rb[wid][3]=s3; rb[wid][4]=s4;
    rb[wid][5]=s5; rb[wid][6]=s6; rb[wid][7]=s7; rb[wid][8]=s8;
  }
  __syncthreads();
  if (tid == 0){
    float S[9];
    for (int k = 0; k < 9; k++){ float a = 0.f; for (int w2 = 0; w2 < 16; w2++) a += rb[w2][k]; S[k] = a; }
    const float inv = 1.f / 8192.f;
    float act_mean = S[2] * inv;
    out[OUT_SSTD] = S[0] * inv;
    out[OUT_ES]   = S[1] * inv;
    out[OUT_ANM]  = act_mean;
    out[OUT_ASTD] = sqrtf(fmaxf(S[3]*inv - act_mean*act_mean, 0.f));
    out[OUT_TAUM] = S[4] * inv;
    out[OUT_Z75]  = S[5] * inv;
    out[OUT_Z30]  = S[6] * inv;
    out[OUT_SKEW] = S[7] * inv;
    out[OUT_ENT]  = S[8] * inv;
    float ms = ns[0] * (1.f / 32768.f);
    float vs = ns[1] * (1.f / 32768.f) - ms*ms;
    out[OUT_SLB] = vs / (ms*ms + vs + 0.01f);
  }
}

// ---------------- launch ----------------

extern "C" void kernel_launch(void* const* d_in, const int* in_sizes, int n_in,
                              void* d_out, int out_size, void* d_ws, size_t ws_size,
                              hipStream_t stream)
{
  (void)in_sizes; (void)n_in; (void)out_size;
  const float* x   = (const float*)d_in[0];
  const float* h   = (const float*)d_in[1];
  const float* emb = (const float*)d_in[2];
  const float* tof = (const float*)d_in[3];
  const float* wr  = (const float*)d_in[4];
  const float* ww  = (const float*)d_in[5];
  float* out = (float*)d_out;
  char* ws = (char*)d_ws;

  size_t off = 0;
  auto get = [&](size_t n){ size_t o = off; off += (n + 255) & ~(size_t)255; return o; };
  unsigned short* rcn_bf = (unsigned short*)(ws + get((size_t)NNEU*DD*2));
  unsigned short* emb_bf = (unsigned short*)(ws + get((size_t)NNEU*DD*2));
  unsigned short* wcnT   = (unsigned short*)(ws + get((size_t)DD*NNEU*2));
  unsigned short* h_bf   = (unsigned short*)(ws + get((size_t)NTOK*DD*2));
  unsigned short* x_bf   = (unsigned short*)(ws + get((size_t)NTOK*DD*2));
  float* inv_w   = (float*)(ws + get(NNEU*4));
  float* tau     = (float*)(ws + get(NTOK*4));
  float* rstd    = (float*)(ws + get(NTOK*4));
  float* wc_comb = (float*)(ws + get(NTOK*4));
  size_t zoff = off;
  float* hsum   = (float*)(ws + get(DD*4));
  float* s_sum  = (float*)(ws + get(NREP*NTOK*4));
  float* sq_sum = (float*)(ws + get(NREP*NTOK*4));
  float* cu_sum = (float*)(ws + get(NREP*NTOK*4));
  float* wcost  = (float*)(ws + get(NREP*NTOK*4));
  float* gmax   = (float*)(ws + get(NREP*NTOK*4));
  float* act    = (float*)(ws + get(NREP*NTOK*4));
  float* strong = (float*)(ws + get(NREP*NTOK*4));
  float* phib   = (float*)(ws + get(NREP*NTOK*4));
  float* zsum   = (float*)(ws + get(NREP*NTOK*4));
  float* z075   = (float*)(ws + get(NREP*NTOK*4));
  float* z030   = (float*)(ws + get(NREP*NTOK*4));
  float* glg    = (float*)(ws + get(NREP*NTOK*4));
  float* ns     = (float*)(ws + get(256));
  size_t zlen = off - zoff;

  const size_t szS = (size_t)NTOK * NC * 2;   // 134.2 MB per chunk
  size_t poff = (off + 4095) & ~(size_t)4095;
  size_t avail = ws_size > poff ? ws_size - poff : 0;
  int kst = (int)(avail / szS);
  if (kst > 4) kst = 4;
  if (kst < 1) kst = 1;
  unsigned short* Sb = (unsigned short*)(ws + poff);

  hipMemsetAsync(ws + zoff, 0, zlen, stream);

  dim3 b256(256);
  dim3 gC(64, 64);   // per-chunk GEMM grid
  k_cast<<<dim3(NTOK*DD/4/256), b256, 0, stream>>>(h, h_bf);
  k_cast<<<dim3(NTOK*DD/4/256), b256, 0, stream>>>(x, x_bf);
  k_hsum<<<dim3(NTOK/128), b256, 0, stream>>>(h_bf, hsum);
  k_rncast<0,1><<<dim3(NNEU/4), b256, 0, stream>>>(emb, emb_bf, hsum, ns);
  k_rncast<1,0><<<dim3(NNEU/4), b256, 0, stream>>>(wr, rcn_bf, nullptr, nullptr);
  k_wnorm<<<dim3(NNEU/4), b256, 0, stream>>>(ww, inv_w);

  // phase 1: score stats over all chunks; store S for first kst chunks
  for (int c = 0; c < 4; ++c){
    unsigned short* slot = Sb + (size_t)(c < kst ? c : 0) * NTOK * NC;
    k_score<true><<<gC, b256, 0, stream>>>(h_bf, emb_bf + (size_t)c*NC*DD,
        s_sum, sq_sum, cu_sum, slot, c < kst ? 1 : 0);
  }
  k_tau<<<dim3(NTOK/256), b256, 0, stream>>>(s_sum, sq_sum, tof, tau, rstd);
  k_wcnT<<<dim3(NNEU/64, DD/64), b256, 0, stream>>>(ww, inv_w, wcnT);

  // phase 2: per chunk: gate (stored-S or dual-GEMM) -> out
  for (int c = 0; c < 4; ++c){
    int slot_i = (c < kst) ? c : (c % kst);
    unsigned short* slot = Sb + (size_t)slot_i * NTOK * NC;
    if (c < kst){
      k_gateS<<<gC, b256, 0, stream>>>(x_bf, rcn_bf, tau, rstd, slot, c*NC,
          wcost, gmax, act, strong, phib, zsum, z075, z030, glg);
    } else {
      k_gate_dual<<<gC, b256, 0, stream>>>(h_bf, emb_bf + (size_t)c*NC*DD,
          x_bf, rcn_bf + (size_t)c*NC*DD, tau, rstd, slot,
          wcost, gmax, act, strong, phib, zsum, z075, z030, glg);
    }
    if (c == 3) k_redw<<<dim3(NTOK/256), b256, 0, stream>>>(wcost, wc_comb);
    k_out_gemm<<<dim3(DD/128, NTOK/128), b256, 0, stream>>>(slot, wcnT + (size_t)c*NC,
        out, wc_comb, c > 0 ? 1 : 0, c == 3 ? 1 : 0);
  }
  k_final<<<dim3(1), dim3(1024), 0, stream>>>(s_sum, sq_sum, cu_sum, tof, wcost, gmax,
      act, strong, phib, zsum, z075, z030, glg, ns, out);
}